// Round 10
// baseline (1127.157 us; speedup 1.0000x reference)
//
#include <hip/hip_runtime.h>
#include <cstddef>

#define NN 50000
#define NE 640000
#define NG 512
#define NL 2
#define NSLOT 16
constexpr float BN_EPS = 1e-5f;

typedef __attribute__((ext_vector_type(8))) short bf16x8;
typedef __attribute__((ext_vector_type(16))) float f32x16;

__device__ inline float b2f_lo(unsigned int u) {
  union { unsigned int i; float f; } v; v.i = u << 16; return v.f;
}
__device__ inline float b2f_hi(unsigned int u) {
  union { unsigned int i; float f; } v; v.i = u & 0xffff0000u; return v.f;
}
__device__ inline unsigned short f2b(float f) {
  union { float f; unsigned int i; } v; v.f = f;
  return (unsigned short)((v.i + 0x7fffu + ((v.i >> 16) & 1u)) >> 16);
}
__device__ inline unsigned int pack2(float lo, float hi) {
  return (unsigned int)f2b(lo) | ((unsigned int)f2b(hi) << 16);
}
// swizzled LDS byte offset for [row][256B]; 16B-aligned, bijective per row
__device__ inline int swz(int row, int b) { return row * 256 + (b ^ ((row & 15) << 4)); }

// Inline BN finalize from raw 16-slot partials (psum at st, psq at st+2048)
__device__ inline void bn_from_stats(const float* __restrict__ st,
                                     const float* __restrict__ gamma,
                                     const float* __restrict__ beta, int c,
                                     float& sc, float& sh) {
  float s = 0.f, s2 = 0.f;
  #pragma unroll
  for (int b = 0; b < NSLOT; ++b) {
    s += st[b * 128 + c];
    s2 += st[2048 + b * 128 + c];
  }
  const float inv_n = 1.f / (float)NN;
  const float mu = s * inv_n;
  const float var = fmaxf(s2 * inv_n - mu * mu, 0.f);
  sc = rsqrtf(var + BN_EPS) * gamma[c];
  sh = beta[c] - mu * sc;
}

// ---------------------------------------------------------------------------
// Gather-fused MFMA GEMM, 32-row tile, EDGE-PARALLEL staging:
// block owns dst rows [row0,row0+32); its CSR edge range is contiguous.
// item = (edge, 16B chunk): 16 consecutive lanes read one full 256B src row
// coalesced; fp32 accumulation via LDS atomics into acc[32][132].
// pck[e] = src | ((dst&31)<<25). Then pack->Au (fragment-major) -> MFMA.
// ---------------------------------------------------------------------------
__global__ __launch_bounds__(256) void gemm_gather32(
    const unsigned short* __restrict__ h, const int* __restrict__ rowptr,
    const int* __restrict__ pck, const unsigned short* __restrict__ Wt,
    const float* __restrict__ bias, unsigned short* __restrict__ C,
    float* __restrict__ psum, float* __restrict__ psq, int n) {
  __shared__ float acc[32][132];   // 16.9 KB, padded vs bank conflicts
  __shared__ uint4 Au[16][32];     // 8 KB  [k-chunk][row]
  __shared__ float colsum[128];
  __shared__ float colsq[128];
  const int t = threadIdx.x;
  const int row0 = blockIdx.x * 32;

  if (t < 128) { colsum[t] = 0.f; colsq[t] = 0.f; }

  const int ln = t & 31;   // row
  const int cg = t >> 5;   // 0..7 -> float16-chunk cg (cols 16cg..16cg+15)
  const int gr = row0 + ln;
  const uint4* h4 = (const uint4*)h;

  // ---- phase 1: init acc with self row (GIN eps=0) ----
  {
    float s[16];
    #pragma unroll
    for (int j = 0; j < 16; ++j) s[j] = 0.f;
    if (gr < n) {
      const uint4 v0 = h4[(size_t)gr * 16 + cg * 2];
      const uint4 v1 = h4[(size_t)gr * 16 + cg * 2 + 1];
      s[0] = b2f_lo(v0.x); s[1] = b2f_hi(v0.x); s[2] = b2f_lo(v0.y); s[3] = b2f_hi(v0.y);
      s[4] = b2f_lo(v0.z); s[5] = b2f_hi(v0.z); s[6] = b2f_lo(v0.w); s[7] = b2f_hi(v0.w);
      s[8]  = b2f_lo(v1.x); s[9]  = b2f_hi(v1.x); s[10] = b2f_lo(v1.y); s[11] = b2f_hi(v1.y);
      s[12] = b2f_lo(v1.z); s[13] = b2f_hi(v1.z); s[14] = b2f_lo(v1.w); s[15] = b2f_hi(v1.w);
    }
    #pragma unroll
    for (int j = 0; j < 16; ++j) acc[ln][cg * 16 + j] = s[j];
  }
  __syncthreads();

  // ---- phase 2: edge-parallel accumulate (no divergence, coalesced rows) ----
  {
    const int rend = min(row0 + 32, n);
    const int E0 = rowptr[row0];
    const int E1 = (rend > row0) ? rowptr[rend] : E0;
    const int items = (E1 - E0) * 16;
    for (int it = t; it < items; it += 256) {
      const int e = E0 + (it >> 4);
      const int q = it & 15;
      const int p = pck[e];
      const int src = p & 0x01FFFFFF;
      const int dl = ((unsigned int)p) >> 25;
      const uint4 v = h4[(size_t)src * 16 + q];
      float* ap = &acc[dl][q * 8];
      atomicAdd(ap + 0, b2f_lo(v.x)); atomicAdd(ap + 1, b2f_hi(v.x));
      atomicAdd(ap + 2, b2f_lo(v.y)); atomicAdd(ap + 3, b2f_hi(v.y));
      atomicAdd(ap + 4, b2f_lo(v.z)); atomicAdd(ap + 5, b2f_hi(v.z));
      atomicAdd(ap + 6, b2f_lo(v.w)); atomicAdd(ap + 7, b2f_hi(v.w));
    }
  }
  __syncthreads();

  // ---- phase 3: pack acc -> Au (fragment-major bf16) ----
  {
    const float* ar = &acc[ln][cg * 16];
    uint4 o0, o1;
    o0.x = pack2(ar[0], ar[1]);   o0.y = pack2(ar[2], ar[3]);
    o0.z = pack2(ar[4], ar[5]);   o0.w = pack2(ar[6], ar[7]);
    o1.x = pack2(ar[8], ar[9]);   o1.y = pack2(ar[10], ar[11]);
    o1.z = pack2(ar[12], ar[13]); o1.w = pack2(ar[14], ar[15]);
    Au[cg * 2][ln] = o0;
    Au[cg * 2 + 1][ln] = o1;
  }
  __syncthreads();

  // ---- MFMA + C-write + stats ----
  const int w = t >> 6;
  const int l = t & 63;
  const int lane31 = l & 31;
  const int khalf = l >> 5;

  f32x16 accv;
  #pragma unroll
  for (int i = 0; i < 16; ++i) accv[i] = 0.f;

  const unsigned short* Bp = Wt + (size_t)(w * 32 + lane31) * 128 + 8 * khalf;
  #pragma unroll
  for (int k0 = 0; k0 < 8; ++k0) {
    const bf16x8 aF = *(const bf16x8*)&Au[k0 * 2 + khalf][lane31];
    const bf16x8 bF = *(const bf16x8*)(Bp + k0 * 16);
    accv = __builtin_amdgcn_mfma_f32_32x32x16_bf16(aF, bF, accv, 0, 0, 0);
  }

  const int col = w * 32 + lane31;
  const float bs = bias[col];
  float s0 = 0.f, q0 = 0.f;
  #pragma unroll
  for (int r = 0; r < 16; ++r) {
    const int row = (r & 3) + 8 * (r >> 2) + 4 * khalf;
    const int grow = row0 + row;
    if (grow < n) {
      const float v = accv[r] + bs;
      C[(size_t)grow * 128 + col] = f2b(v);
      s0 += v; q0 = fmaf(v, v, q0);
    }
  }
  atomicAdd(&colsum[col], s0);
  atomicAdd(&colsq[col], q0);
  __syncthreads();
  if (t < 128) {
    const int slot = blockIdx.x & (NSLOT - 1);
    atomicAdd(&psum[slot * 128 + t], colsum[t]);
    atomicAdd(&psq[slot * 128 + t], colsq[t]);
  }
}

// ---------------------------------------------------------------------------
// Fused MFMA GEMM (64-row tile):
// MODE 2: A=relu(bf16 A*scale+shift), scale/shift from raw stIn (in-place ok)
// MODE 3: A = fp32 input. B read from global Wt (L1-resident).
// ---------------------------------------------------------------------------
template <int MODE, bool STATS>
__global__ __launch_bounds__(256) void gemm_fused(
    const void* __restrict__ Ain, const float* __restrict__ stIn,
    const float* __restrict__ gIn, const float* __restrict__ beIn,
    const unsigned short* __restrict__ Wt, const float* __restrict__ bias,
    unsigned short* __restrict__ C, float* __restrict__ psum,
    float* __restrict__ psq, int n) {
  __shared__ char Al[16384];
  __shared__ float colsum[128];
  __shared__ float colsq[128];
  __shared__ float sc_s[128], sh_s[128];
  const int t = threadIdx.x;
  const int row0 = blockIdx.x * 64;

  if (t < 128) {
    if (STATS) { colsum[t] = 0.f; colsq[t] = 0.f; }
    if (MODE == 2) {
      float a, b;
      bn_from_stats(stIn, gIn, beIn, t, a, b);
      sc_s[t] = a; sh_s[t] = b;
    }
  }
  if (MODE == 2) __syncthreads();

  #pragma unroll
  for (int ii = 0; ii < 4; ++ii) {
    const int i = t + ii * 256;
    const int r = i >> 4;
    const int u = (i & 15) << 4;
    const int gr = row0 + r;
    uint4 v = make_uint4(0u, 0u, 0u, 0u);
    if (gr < n) {
      if (MODE == 3) {
        const float* Af = (const float*)Ain;
        const float4 f0 = *(const float4*)(Af + (size_t)gr * 128 + (u >> 1));
        const float4 f1 = *(const float4*)(Af + (size_t)gr * 128 + (u >> 1) + 4);
        v.x = pack2(f0.x, f0.y); v.y = pack2(f0.z, f0.w);
        v.z = pack2(f1.x, f1.y); v.w = pack2(f1.z, f1.w);
      } else {
        v = *(const uint4*)((const char*)Ain + (size_t)gr * 256 + u);
        const int c0 = u >> 1;
        unsigned int pw[4] = {v.x, v.y, v.z, v.w};
        #pragma unroll
        for (int p = 0; p < 4; ++p) {
          float lo = b2f_lo(pw[p]);
          float hi = b2f_hi(pw[p]);
          lo = fmaxf(fmaf(lo, sc_s[c0 + 2 * p], sh_s[c0 + 2 * p]), 0.f);
          hi = fmaxf(fmaf(hi, sc_s[c0 + 2 * p + 1], sh_s[c0 + 2 * p + 1]), 0.f);
          pw[p] = pack2(lo, hi);
        }
        v = make_uint4(pw[0], pw[1], pw[2], pw[3]);
      }
    }
    *(uint4*)(Al + swz(r, u)) = v;
  }
  __syncthreads();

  const int w = t >> 6;
  const int l = t & 63;
  const int lane31 = l & 31;
  const int khalf = l >> 5;
  const int mrow = (w & 1) * 32;
  const int c0 = (w >> 1) * 64;

  f32x16 acc0, acc1;
  #pragma unroll
  for (int i = 0; i < 16; ++i) { acc0[i] = 0.f; acc1[i] = 0.f; }

  const unsigned short* Bp0 = Wt + (size_t)(c0 + lane31) * 128 + 8 * khalf;
  const unsigned short* Bp1 = Wt + (size_t)(c0 + 32 + lane31) * 128 + 8 * khalf;

  #pragma unroll
  for (int k0 = 0; k0 < 128; k0 += 16) {
    const int kb = (k0 + 8 * khalf) * 2;
    const bf16x8 a  = *(const bf16x8*)(Al + swz(mrow + lane31, kb));
    const bf16x8 b0 = *(const bf16x8*)(Bp0 + k0);
    const bf16x8 b1 = *(const bf16x8*)(Bp1 + k0);
    acc0 = __builtin_amdgcn_mfma_f32_32x32x16_bf16(a, b0, acc0, 0, 0, 0);
    acc1 = __builtin_amdgcn_mfma_f32_32x32x16_bf16(a, b1, acc1, 0, 0, 0);
  }

  const float bias0 = bias[c0 + lane31];
  const float bias1 = bias[c0 + 32 + lane31];
  float s0 = 0.f, q0 = 0.f, s1 = 0.f, q1 = 0.f;
  #pragma unroll
  for (int r = 0; r < 16; ++r) {
    const int row = mrow + (r & 3) + 8 * (r >> 2) + 4 * khalf;
    const int grow = row0 + row;
    if (grow < n) {
      const float v0 = acc0[r] + bias0;
      const float v1 = acc1[r] + bias1;
      C[(size_t)grow * 128 + c0 + lane31] = f2b(v0);
      C[(size_t)grow * 128 + c0 + 32 + lane31] = f2b(v1);
      if (STATS) {
        s0 += v0; q0 = fmaf(v0, v0, q0);
        s1 += v1; q1 = fmaf(v1, v1, q1);
      }
    }
  }
  if (STATS) {
    atomicAdd(&colsum[c0 + lane31], s0);
    atomicAdd(&colsq[c0 + lane31], q0);
    atomicAdd(&colsum[c0 + 32 + lane31], s1);
    atomicAdd(&colsq[c0 + 32 + lane31], q1);
    __syncthreads();
    if (t < 128) {
      const int slot = blockIdx.x & (NSLOT - 1);
      atomicAdd(&psum[slot * 128 + t], colsum[t]);
      atomicAdd(&psq[slot * 128 + t], colsq[t]);
    }
  }
}

// ---------------------------------------------------------------------------
// Fused setup: weight conversion + cnt/stats zero + graph segment search
// ---------------------------------------------------------------------------
__global__ __launch_bounds__(256) void setup_k(
    const float* __restrict__ lw, const float* __restrict__ w1,
    const float* __restrict__ w2, unsigned short* __restrict__ Wt,
    const int* __restrict__ batch, int* __restrict__ gstart,
    float* __restrict__ counts, int* __restrict__ cnt,
    float* __restrict__ stats) {
  const int b = blockIdx.x, t = threadIdx.x;
  if (b < 320) {  // weight convert (5*16384)
    const int i = b * 256 + t;
    const int m = i >> 14, r = i & 16383;
    const int ncol = r >> 7, k = r & 127;
    const float* src = (m == 0) ? lw : (m <= 2) ? (w1 + (m - 1) * 16384)
                                                : (w2 + (m - 3) * 16384);
    Wt[i] = f2b(src[k * 128 + ncol]);
  } else if (b < 516) {  // zero cnt (50000)
    const int i = (b - 320) * 256 + t;
    if (i < NN) cnt[i] = 0;
  } else if (b < 580) {  // zero stats (4*4096)
    stats[(b - 516) * 256 + t] = 0.f;
  } else {  // segments (NG+1)
    const int g = (b - 580) * 256 + t;
    if (g > NG) return;
    int lo = 0, hi = NN;
    while (lo < hi) { int m = (lo + hi) >> 1; if (batch[m] < g) lo = m + 1; else hi = m; }
    gstart[g] = lo;
    if (g < NG) {
      int lo1 = lo, hi1 = NN;
      while (lo1 < hi1) { int m = (lo1 + hi1) >> 1; if (batch[m] < g + 1) lo1 = m + 1; else hi1 = m; }
      counts[g] = (float)(lo1 - lo);
    }
  }
}

// ---------------------------------------------------------------------------
// CSR build: histogram -> hierarchical scan -> bucket fill (cursor = cnt)
// ---------------------------------------------------------------------------
#define SCAN_B 196
__global__ __launch_bounds__(256) void edge_hist(const int* __restrict__ ei,
                                                 int* __restrict__ cnt) {
  const int e = blockIdx.x * 256 + threadIdx.x;
  if (e >= NE) return;
  atomicAdd(&cnt[ei[NE + e]], 1);
}

__global__ __launch_bounds__(256) void scan1(const int* __restrict__ cnt,
                                             int* __restrict__ rowptr,
                                             int* __restrict__ bsum) {
  __shared__ int s[256];
  const int b = blockIdx.x, t = threadIdx.x;
  const int i = b * 256 + t;
  const int v = (i < NN) ? cnt[i] : 0;
  s[t] = v;
  __syncthreads();
  for (int off = 1; off < 256; off <<= 1) {
    const int x = (t >= off) ? s[t - off] : 0;
    __syncthreads();
    s[t] += x;
    __syncthreads();
  }
  if (i < NN) rowptr[i] = s[t] - v;
  if (t == 255) bsum[b] = s[255];
}

__global__ __launch_bounds__(256) void scan2(const int* __restrict__ bsum,
                                             int* __restrict__ boff,
                                             int* __restrict__ rowptrN) {
  __shared__ int s[256];
  const int t = threadIdx.x;
  const int v = (t < SCAN_B) ? bsum[t] : 0;
  s[t] = v;
  __syncthreads();
  for (int off = 1; off < 256; off <<= 1) {
    const int x = (t >= off) ? s[t - off] : 0;
    __syncthreads();
    s[t] += x;
    __syncthreads();
  }
  if (t < SCAN_B) boff[t] = s[t] - v;
  if (t == 255) *rowptrN = s[255];
}

__global__ __launch_bounds__(256) void scan3(int* __restrict__ rowptr,
                                             const int* __restrict__ boff,
                                             int* __restrict__ cursor) {
  const int i = blockIdx.x * 256 + threadIdx.x;
  if (i < NN) {
    const int v = rowptr[i] + boff[blockIdx.x];
    rowptr[i] = v;
    cursor[i] = v;
  }
}

// writes packed entries: src | ((dst&31)<<25)
__global__ __launch_bounds__(256) void build_csr(const int* __restrict__ ei,
                                                 int* __restrict__ cursor,
                                                 int* __restrict__ pck) {
  const int e = blockIdx.x * 256 + threadIdx.x;
  if (e >= NE) return;
  const int src = ei[e];
  const int dst = ei[NE + e];
  const int pos = atomicAdd(&cursor[dst], 1);
  pck[pos] = src | ((dst & 31) << 25);
}

// ---------------------------------------------------------------------------
// Per-graph fused BN+ReLU+mean-pool (bf16 in); BN derived inline.
// WRITE_H: writes h = relu(bn(Z)) for next layer. FINAL: emits out[g]
// directly (layer-1), reading layer-0 pooled from global + layer-1 from LDS.
// ---------------------------------------------------------------------------
template <bool WRITE_H, bool FINAL>
__global__ __launch_bounds__(256) void bn_relu_pool_seg_b(
    const unsigned short* __restrict__ Z, const float* __restrict__ stIn,
    const float* __restrict__ gIn, const float* __restrict__ beIn,
    const int* __restrict__ gstart, unsigned short* __restrict__ h,
    float* __restrict__ pooled, int layerOff,
    const float* __restrict__ counts, const float* __restrict__ jkw,
    const float* __restrict__ jkb, float* __restrict__ out) {
  __shared__ float sc_s[128], sh_s[128];
  __shared__ float red[256 * 8];
  const int g = blockIdx.x;
  const int t = threadIdx.x;
  if (t < 128) {
    float a, b;
    bn_from_stats(stIn, gIn, beIn, t, a, b);
    sc_s[t] = a; sh_s[t] = b;
  }
  __syncthreads();
  const int r0 = gstart[g], r1 = gstart[g + 1];
  const int q = t & 15;
  const int rr = t >> 4;
  const int c0 = q * 8;
  float sc[8], sh[8], acc[8];
  #pragma unroll
  for (int i = 0; i < 8; ++i) { sc[i] = sc_s[c0 + i]; sh[i] = sh_s[c0 + i]; acc[i] = 0.f; }
  for (int r = r0 + rr; r < r1; r += 16) {
    const uint4 v = ((const uint4*)Z)[(size_t)r * 16 + q];
    float o[8];
    o[0] = b2f_lo(v.x); o[1] = b2f_hi(v.x); o[2] = b2f_lo(v.y); o[3] = b2f_hi(v.y);
    o[4] = b2f_lo(v.z); o[5] = b2f_hi(v.z); o[6] = b2f_lo(v.w); o[7] = b2f_hi(v.w);
    #pragma unroll
    for (int i = 0; i < 8; ++i) {
      o[i] = fmaxf(fmaf(o[i], sc[i], sh[i]), 0.f);
      acc[i] += o[i];
    }
    if (WRITE_H) {
      uint4 ov;
      ov.x = pack2(o[0], o[1]); ov.y = pack2(o[2], o[3]);
      ov.z = pack2(o[4], o[5]); ov.w = pack2(o[6], o[7]);
      ((uint4*)h)[(size_t)r * 16 + q] = ov;
    }
  }
  #pragma unroll
  for (int i = 0; i < 8; ++i) red[t * 8 + i] = acc[i];
  __syncthreads();
  for (int off = 8; off >= 1; off >>= 1) {
    if (rr < off) {
      #pragma unroll
      for (int i = 0; i < 8; ++i)
        red[t * 8 + i] += red[(t + off * 16) * 8 + i];
    }
    __syncthreads();
  }
  // red[0..127] now holds this layer's pooled sums (index = channel)
  if (!FINAL) {
    if (rr == 0) {
      #pragma unroll
      for (int i = 0; i < 8; ++i)
        pooled[(size_t)g * 256 + layerOff + c0 + i] = red[t * 8 + i];
    }
  } else {
    float part = 0.f;
    if (t < 128)
      part = pooled[(size_t)g * 256 + t] * jkw[t] + red[t] * jkw[128 + t];
    red[1024 + t] = part;
    __syncthreads();
    for (int off = 64; off >= 1; off >>= 1) {
      if (t < off) red[1024 + t] += red[1024 + t + off];
      __syncthreads();
    }
    if (t == 0)
      out[g] = red[1024] / fmaxf(counts[g], 1.f) + jkb[0];
  }
}

// ---------------------------------------------------------------------------
extern "C" void kernel_launch(void* const* d_in, const int* in_sizes, int n_in,
                              void* d_out, int out_size, void* d_ws,
                              size_t ws_size, hipStream_t stream) {
  const float* x     = (const float*)d_in[0];
  const int*   ei    = (const int*)d_in[1];
  const int*   batch = (const int*)d_in[2];
  const float* lin_w = (const float*)d_in[3];
  const float* lin_b = (const float*)d_in[4];
  const float* w1    = (const float*)d_in[5];
  const float* b1    = (const float*)d_in[6];
  const float* g1    = (const float*)d_in[7];
  const float* be1   = (const float*)d_in[8];
  const float* w2    = (const float*)d_in[9];
  const float* b2    = (const float*)d_in[10];
  const float* g2    = (const float*)d_in[11];
  const float* be2   = (const float*)d_in[12];
  const float* jkw   = (const float*)d_in[13];
  const float* jkb   = (const float*)d_in[14];
  float* out = (float*)d_out;

  char* base = (char*)d_ws;
  unsigned short* hb  = (unsigned short*)base;                 // NN*128 bf16 (buffer A)
  unsigned short* agb = hb + (size_t)NN * 128;                 // NN*128 bf16 (buffer B)
  unsigned short* WtA = agb + (size_t)NN * 128;                // 5*16384 bf16
  float* pooled = (float*)(WtA + 5 * 16384);                   // NG*256
  float* counts = pooled + (size_t)NG * 256;                   // NG
  int* gstart = (int*)(counts + NG);                           // NG+1 (+pad)
  int* rowptr = gstart + NG + 4;                               // NN+1 (+pad)
  int* bsum   = rowptr + NN + 4;                               // 196 (+pad)
  int* boff   = bsum + 200;                                    // 196 (+pad)
  int* pck    = boff + 200;                                    // NE
  int* cnt    = pck + NE;                                      // NN   (zeroed)
  float* stats = (float*)(cnt + NN);                           // 4*4096 (zeroed)
  // stats set s (0..3): psum = stats + s*4096, psq = psum + 2048

  setup_k<<<583, 256, 0, stream>>>(lin_w, w1, w2, WtA, batch, gstart, counts,
                                   cnt, stats);

  // CSR build (by dst)
  edge_hist<<<(NE + 255) / 256, 256, 0, stream>>>(ei, cnt);
  scan1<<<SCAN_B, 256, 0, stream>>>(cnt, rowptr, bsum);
  scan2<<<1, 256, 0, stream>>>(bsum, boff, rowptr + NN);
  scan3<<<SCAN_B, 256, 0, stream>>>(rowptr, boff, cnt);
  build_csr<<<(NE + 255) / 256, 256, 0, stream>>>(ei, cnt, pck);

  const int gemm_grid = (NN + 63) / 64;      // 782
  const int gath_grid = (NN + 31) / 32;      // 1563

  float* st1_0 = stats;
  float* st2_0 = stats + 4096;
  float* st1_1 = stats + 2 * 4096;
  float* st2_1 = stats + 3 * 4096;

  // h0 = x @ lin_w + lin_b  (fp32 input read directly) -> A
  gemm_fused<3, false><<<gemm_grid, 256, 0, stream>>>(
      x, nullptr, nullptr, nullptr, WtA, lin_b, hb, nullptr, nullptr, NN);

  // ---- layer 0 ----
  gemm_gather32<<<gath_grid, 256, 0, stream>>>(
      hb, rowptr, pck, WtA + 1 * 16384, b1, agb, st1_0, st1_0 + 2048, NN);
  gemm_fused<2, true><<<gemm_grid, 256, 0, stream>>>(
      agb, st1_0, g1, be1, WtA + 3 * 16384, b2, agb, st2_0, st2_0 + 2048, NN);
  // pool layer 0 + write h1 = relu(bn(z2)) into A (h0 is dead)
  bn_relu_pool_seg_b<true, false><<<NG, 256, 0, stream>>>(
      agb, st2_0, g2, be2, gstart, hb, pooled, 0,
      nullptr, nullptr, nullptr, nullptr);

  // ---- layer 1 ----
  gemm_gather32<<<gath_grid, 256, 0, stream>>>(
      hb, rowptr, pck, WtA + 2 * 16384, b1 + 128, agb, st1_1, st1_1 + 2048, NN);
  gemm_fused<2, true><<<gemm_grid, 256, 0, stream>>>(
      agb, st1_1, g1 + 128, be1 + 128, WtA + 4 * 16384, b2 + 128, agb,
      st2_1, st2_1 + 2048, NN);
  // pool layer 1 + final projection (emits out directly)
  bn_relu_pool_seg_b<false, true><<<NG, 256, 0, stream>>>(
      agb, st2_1, g2 + 128, be2 + 128, gstart, nullptr, pooled, 128,
      counts, jkw, jkb, out);
}

// Round 11
// 240.194 us; speedup vs baseline: 4.6927x; 4.6927x over previous
//
#include <hip/hip_runtime.h>
#include <cstddef>

#define NN 50000
#define NE 640000
#define NG 512
#define NL 2
#define NSLOT 16
constexpr float BN_EPS = 1e-5f;

typedef __attribute__((ext_vector_type(8))) short bf16x8;
typedef __attribute__((ext_vector_type(16))) float f32x16;

__device__ inline float b2f_lo(unsigned int u) {
  union { unsigned int i; float f; } v; v.i = u << 16; return v.f;
}
__device__ inline float b2f_hi(unsigned int u) {
  union { unsigned int i; float f; } v; v.i = u & 0xffff0000u; return v.f;
}
__device__ inline unsigned short f2b(float f) {
  union { float f; unsigned int i; } v; v.f = f;
  return (unsigned short)((v.i + 0x7fffu + ((v.i >> 16) & 1u)) >> 16);
}
__device__ inline unsigned int pack2(float lo, float hi) {
  return (unsigned int)f2b(lo) | ((unsigned int)f2b(hi) << 16);
}
// swizzled LDS byte offset for [row][256B]; 16B-aligned, bijective per row
__device__ inline int swz(int row, int b) { return row * 256 + (b ^ ((row & 15) << 4)); }

__device__ inline void unpack_add(const uint4 v, float* a) {
  a[0] += b2f_lo(v.x); a[1] += b2f_hi(v.x); a[2] += b2f_lo(v.y); a[3] += b2f_hi(v.y);
  a[4] += b2f_lo(v.z); a[5] += b2f_hi(v.z); a[6] += b2f_lo(v.w); a[7] += b2f_hi(v.w);
}

// Inline BN finalize from raw 16-slot partials (psum at st, psq at st+2048)
__device__ inline void bn_from_stats(const float* __restrict__ st,
                                     const float* __restrict__ gamma,
                                     const float* __restrict__ beta, int c,
                                     float& sc, float& sh) {
  float s = 0.f, s2 = 0.f;
  #pragma unroll
  for (int b = 0; b < NSLOT; ++b) {
    s += st[b * 128 + c];
    s2 += st[2048 + b * 128 + c];
  }
  const float inv_n = 1.f / (float)NN;
  const float mu = s * inv_n;
  const float var = fmaxf(s2 * inv_n - mu * mu, 0.f);
  sc = rsqrtf(var + BN_EPS) * gamma[c];
  sh = beta[c] - mu * sc;
}

// ---------------------------------------------------------------------------
// Gather-fused MFMA GEMM, 32-row tile (row-parallel, proven R9 form):
// C = (gather(h)) @ W + bias, with fused column stats.
// 256 thr = 4 waves; 8 threads/row gather (2x16B each), fragment-major LDS.
// pck[e] = src | ((dst&31)<<25) — src masked out here.
// ---------------------------------------------------------------------------
__global__ __launch_bounds__(256) void gemm_gather32(
    const unsigned short* __restrict__ h, const int* __restrict__ rowptr,
    const int* __restrict__ pck, const unsigned short* __restrict__ Wt,
    const float* __restrict__ bias, unsigned short* __restrict__ C,
    float* __restrict__ psum, float* __restrict__ psq, int n) {
  __shared__ uint4 Au[16][32];  // [k-chunk][row], 8 KB
  __shared__ float colsum[128];
  __shared__ float colsq[128];
  const int t = threadIdx.x;
  const int row0 = blockIdx.x * 32;

  if (t < 128) { colsum[t] = 0.f; colsq[t] = 0.f; }

  const int ln = t & 31;   // row
  const int cg = t >> 5;   // 0..7 -> chunks cg*2, cg*2+1
  const int gr = row0 + ln;
  const uint4* h4 = (const uint4*)h;
  float a0[8], a1[8];
  #pragma unroll
  for (int p = 0; p < 8; ++p) { a0[p] = 0.f; a1[p] = 0.f; }
  if (gr < n) {
    {
      const uint4* p = &h4[(size_t)gr * 16 + cg * 2];
      unpack_add(p[0], a0); unpack_add(p[1], a1);
    }
    const int beg = rowptr[gr], end = rowptr[gr + 1];
    int j = beg;
    for (; j + 1 < end; j += 2) {
      const int s0i = pck[j] & 0x01FFFFFF;
      const int s1i = pck[j + 1] & 0x01FFFFFF;
      const uint4* p0 = &h4[(size_t)s0i * 16 + cg * 2];
      const uint4* p1 = &h4[(size_t)s1i * 16 + cg * 2];
      const uint4 v00 = p0[0], v01 = p0[1];
      const uint4 v10 = p1[0], v11 = p1[1];
      unpack_add(v00, a0); unpack_add(v01, a1);
      unpack_add(v10, a0); unpack_add(v11, a1);
    }
    if (j < end) {
      const int s0i = pck[j] & 0x01FFFFFF;
      const uint4* p0 = &h4[(size_t)s0i * 16 + cg * 2];
      unpack_add(p0[0], a0); unpack_add(p0[1], a1);
    }
  }
  {
    uint4 o0, o1;
    o0.x = pack2(a0[0], a0[1]); o0.y = pack2(a0[2], a0[3]);
    o0.z = pack2(a0[4], a0[5]); o0.w = pack2(a0[6], a0[7]);
    o1.x = pack2(a1[0], a1[1]); o1.y = pack2(a1[2], a1[3]);
    o1.z = pack2(a1[4], a1[5]); o1.w = pack2(a1[6], a1[7]);
    Au[cg * 2][ln] = o0;
    Au[cg * 2 + 1][ln] = o1;
  }
  __syncthreads();

  const int w = t >> 6;
  const int l = t & 63;
  const int lane31 = l & 31;
  const int khalf = l >> 5;

  f32x16 acc;
  #pragma unroll
  for (int i = 0; i < 16; ++i) acc[i] = 0.f;

  const unsigned short* Bp = Wt + (size_t)(w * 32 + lane31) * 128 + 8 * khalf;
  #pragma unroll
  for (int k0 = 0; k0 < 8; ++k0) {
    const bf16x8 aF = *(const bf16x8*)&Au[k0 * 2 + khalf][lane31];
    const bf16x8 bF = *(const bf16x8*)(Bp + k0 * 16);
    acc = __builtin_amdgcn_mfma_f32_32x32x16_bf16(aF, bF, acc, 0, 0, 0);
  }

  const int col = w * 32 + lane31;
  const float bs = bias[col];
  float s0 = 0.f, q0 = 0.f;
  #pragma unroll
  for (int r = 0; r < 16; ++r) {
    const int row = (r & 3) + 8 * (r >> 2) + 4 * khalf;
    const int grow = row0 + row;
    if (grow < n) {
      const float v = acc[r] + bs;
      C[(size_t)grow * 128 + col] = f2b(v);
      s0 += v; q0 = fmaf(v, v, q0);
    }
  }
  atomicAdd(&colsum[col], s0);
  atomicAdd(&colsq[col], q0);
  __syncthreads();
  if (t < 128) {
    const int slot = blockIdx.x & (NSLOT - 1);
    atomicAdd(&psum[slot * 128 + t], colsum[t]);
    atomicAdd(&psq[slot * 128 + t], colsq[t]);
  }
}

// ---------------------------------------------------------------------------
// Fused MFMA GEMM (64-row tile):
// MODE 2: A=relu(bf16 A*scale+shift), scale/shift from raw stIn (in-place ok)
// MODE 3: A = fp32 input. B read from global Wt (L1-resident).
// ---------------------------------------------------------------------------
template <int MODE, bool STATS>
__global__ __launch_bounds__(256) void gemm_fused(
    const void* __restrict__ Ain, const float* __restrict__ stIn,
    const float* __restrict__ gIn, const float* __restrict__ beIn,
    const unsigned short* __restrict__ Wt, const float* __restrict__ bias,
    unsigned short* __restrict__ C, float* __restrict__ psum,
    float* __restrict__ psq, int n) {
  __shared__ char Al[16384];
  __shared__ float colsum[128];
  __shared__ float colsq[128];
  __shared__ float sc_s[128], sh_s[128];
  const int t = threadIdx.x;
  const int row0 = blockIdx.x * 64;

  if (t < 128) {
    if (STATS) { colsum[t] = 0.f; colsq[t] = 0.f; }
    if (MODE == 2) {
      float a, b;
      bn_from_stats(stIn, gIn, beIn, t, a, b);
      sc_s[t] = a; sh_s[t] = b;
    }
  }
  if (MODE == 2) __syncthreads();

  #pragma unroll
  for (int ii = 0; ii < 4; ++ii) {
    const int i = t + ii * 256;
    const int r = i >> 4;
    const int u = (i & 15) << 4;
    const int gr = row0 + r;
    uint4 v = make_uint4(0u, 0u, 0u, 0u);
    if (gr < n) {
      if (MODE == 3) {
        const float* Af = (const float*)Ain;
        const float4 f0 = *(const float4*)(Af + (size_t)gr * 128 + (u >> 1));
        const float4 f1 = *(const float4*)(Af + (size_t)gr * 128 + (u >> 1) + 4);
        v.x = pack2(f0.x, f0.y); v.y = pack2(f0.z, f0.w);
        v.z = pack2(f1.x, f1.y); v.w = pack2(f1.z, f1.w);
      } else {
        v = *(const uint4*)((const char*)Ain + (size_t)gr * 256 + u);
        const int c0 = u >> 1;
        unsigned int pw[4] = {v.x, v.y, v.z, v.w};
        #pragma unroll
        for (int p = 0; p < 4; ++p) {
          float lo = b2f_lo(pw[p]);
          float hi = b2f_hi(pw[p]);
          lo = fmaxf(fmaf(lo, sc_s[c0 + 2 * p], sh_s[c0 + 2 * p]), 0.f);
          hi = fmaxf(fmaf(hi, sc_s[c0 + 2 * p + 1], sh_s[c0 + 2 * p + 1]), 0.f);
          pw[p] = pack2(lo, hi);
        }
        v = make_uint4(pw[0], pw[1], pw[2], pw[3]);
      }
    }
    *(uint4*)(Al + swz(r, u)) = v;
  }
  __syncthreads();

  const int w = t >> 6;
  const int l = t & 63;
  const int lane31 = l & 31;
  const int khalf = l >> 5;
  const int mrow = (w & 1) * 32;
  const int c0 = (w >> 1) * 64;

  f32x16 acc0, acc1;
  #pragma unroll
  for (int i = 0; i < 16; ++i) { acc0[i] = 0.f; acc1[i] = 0.f; }

  const unsigned short* Bp0 = Wt + (size_t)(c0 + lane31) * 128 + 8 * khalf;
  const unsigned short* Bp1 = Wt + (size_t)(c0 + 32 + lane31) * 128 + 8 * khalf;

  #pragma unroll
  for (int k0 = 0; k0 < 128; k0 += 16) {
    const int kb = (k0 + 8 * khalf) * 2;
    const bf16x8 a  = *(const bf16x8*)(Al + swz(mrow + lane31, kb));
    const bf16x8 b0 = *(const bf16x8*)(Bp0 + k0);
    const bf16x8 b1 = *(const bf16x8*)(Bp1 + k0);
    acc0 = __builtin_amdgcn_mfma_f32_32x32x16_bf16(a, b0, acc0, 0, 0, 0);
    acc1 = __builtin_amdgcn_mfma_f32_32x32x16_bf16(a, b1, acc1, 0, 0, 0);
  }

  const float bias0 = bias[c0 + lane31];
  const float bias1 = bias[c0 + 32 + lane31];
  float s0 = 0.f, q0 = 0.f, s1 = 0.f, q1 = 0.f;
  #pragma unroll
  for (int r = 0; r < 16; ++r) {
    const int row = mrow + (r & 3) + 8 * (r >> 2) + 4 * khalf;
    const int grow = row0 + row;
    if (grow < n) {
      const float v0 = acc0[r] + bias0;
      const float v1 = acc1[r] + bias1;
      C[(size_t)grow * 128 + c0 + lane31] = f2b(v0);
      C[(size_t)grow * 128 + c0 + 32 + lane31] = f2b(v1);
      if (STATS) {
        s0 += v0; q0 = fmaf(v0, v0, q0);
        s1 += v1; q1 = fmaf(v1, v1, q1);
      }
    }
  }
  if (STATS) {
    atomicAdd(&colsum[c0 + lane31], s0);
    atomicAdd(&colsq[c0 + lane31], q0);
    atomicAdd(&colsum[c0 + 32 + lane31], s1);
    atomicAdd(&colsq[c0 + 32 + lane31], q1);
    __syncthreads();
    if (t < 128) {
      const int slot = blockIdx.x & (NSLOT - 1);
      atomicAdd(&psum[slot * 128 + t], colsum[t]);
      atomicAdd(&psq[slot * 128 + t], colsq[t]);
    }
  }
}

// ---------------------------------------------------------------------------
// Fused setup: weight conversion + cnt/stats zero + graph segment search
// ---------------------------------------------------------------------------
__global__ __launch_bounds__(256) void setup_k(
    const float* __restrict__ lw, const float* __restrict__ w1,
    const float* __restrict__ w2, unsigned short* __restrict__ Wt,
    const int* __restrict__ batch, int* __restrict__ gstart,
    float* __restrict__ counts, int* __restrict__ cnt,
    float* __restrict__ stats) {
  const int b = blockIdx.x, t = threadIdx.x;
  if (b < 320) {  // weight convert (5*16384)
    const int i = b * 256 + t;
    const int m = i >> 14, r = i & 16383;
    const int ncol = r >> 7, k = r & 127;
    const float* src = (m == 0) ? lw : (m <= 2) ? (w1 + (m - 1) * 16384)
                                                : (w2 + (m - 3) * 16384);
    Wt[i] = f2b(src[k * 128 + ncol]);
  } else if (b < 516) {  // zero cnt (50000)
    const int i = (b - 320) * 256 + t;
    if (i < NN) cnt[i] = 0;
  } else if (b < 580) {  // zero stats (4*4096)
    stats[(b - 516) * 256 + t] = 0.f;
  } else {  // segments (NG+1)
    const int g = (b - 580) * 256 + t;
    if (g > NG) return;
    int lo = 0, hi = NN;
    while (lo < hi) { int m = (lo + hi) >> 1; if (batch[m] < g) lo = m + 1; else hi = m; }
    gstart[g] = lo;
    if (g < NG) {
      int lo1 = lo, hi1 = NN;
      while (lo1 < hi1) { int m = (lo1 + hi1) >> 1; if (batch[m] < g + 1) lo1 = m + 1; else hi1 = m; }
      counts[g] = (float)(lo1 - lo);
    }
  }
}

// ---------------------------------------------------------------------------
// CSR build: histogram -> hierarchical scan -> bucket fill (cursor = cnt)
// ---------------------------------------------------------------------------
#define SCAN_B 196
__global__ __launch_bounds__(256) void edge_hist(const int* __restrict__ ei,
                                                 int* __restrict__ cnt) {
  const int e = blockIdx.x * 256 + threadIdx.x;
  if (e >= NE) return;
  atomicAdd(&cnt[ei[NE + e]], 1);
}

__global__ __launch_bounds__(256) void scan1(const int* __restrict__ cnt,
                                             int* __restrict__ rowptr,
                                             int* __restrict__ bsum) {
  __shared__ int s[256];
  const int b = blockIdx.x, t = threadIdx.x;
  const int i = b * 256 + t;
  const int v = (i < NN) ? cnt[i] : 0;
  s[t] = v;
  __syncthreads();
  for (int off = 1; off < 256; off <<= 1) {
    const int x = (t >= off) ? s[t - off] : 0;
    __syncthreads();
    s[t] += x;
    __syncthreads();
  }
  if (i < NN) rowptr[i] = s[t] - v;
  if (t == 255) bsum[b] = s[255];
}

__global__ __launch_bounds__(256) void scan2(const int* __restrict__ bsum,
                                             int* __restrict__ boff,
                                             int* __restrict__ rowptrN) {
  __shared__ int s[256];
  const int t = threadIdx.x;
  const int v = (t < SCAN_B) ? bsum[t] : 0;
  s[t] = v;
  __syncthreads();
  for (int off = 1; off < 256; off <<= 1) {
    const int x = (t >= off) ? s[t - off] : 0;
    __syncthreads();
    s[t] += x;
    __syncthreads();
  }
  if (t < SCAN_B) boff[t] = s[t] - v;
  if (t == 255) *rowptrN = s[255];
}

__global__ __launch_bounds__(256) void scan3(int* __restrict__ rowptr,
                                             const int* __restrict__ boff,
                                             int* __restrict__ cursor) {
  const int i = blockIdx.x * 256 + threadIdx.x;
  if (i < NN) {
    const int v = rowptr[i] + boff[blockIdx.x];
    rowptr[i] = v;
    cursor[i] = v;
  }
}

// writes packed entries: src | ((dst&31)<<25)
__global__ __launch_bounds__(256) void build_csr(const int* __restrict__ ei,
                                                 int* __restrict__ cursor,
                                                 int* __restrict__ pck) {
  const int e = blockIdx.x * 256 + threadIdx.x;
  if (e >= NE) return;
  const int src = ei[e];
  const int dst = ei[NE + e];
  const int pos = atomicAdd(&cursor[dst], 1);
  pck[pos] = src | ((dst & 31) << 25);
}

// ---------------------------------------------------------------------------
// Per-graph fused BN+ReLU+mean-pool (bf16 in); BN derived inline.
// WRITE_H: writes h = relu(bn(Z)) for next layer. FINAL: emits out[g]
// directly (layer-1), reading layer-0 pooled from global + layer-1 from LDS.
// ---------------------------------------------------------------------------
template <bool WRITE_H, bool FINAL>
__global__ __launch_bounds__(256) void bn_relu_pool_seg_b(
    const unsigned short* __restrict__ Z, const float* __restrict__ stIn,
    const float* __restrict__ gIn, const float* __restrict__ beIn,
    const int* __restrict__ gstart, unsigned short* __restrict__ h,
    float* __restrict__ pooled, int layerOff,
    const float* __restrict__ counts, const float* __restrict__ jkw,
    const float* __restrict__ jkb, float* __restrict__ out) {
  __shared__ float sc_s[128], sh_s[128];
  __shared__ float red[256 * 8];
  const int g = blockIdx.x;
  const int t = threadIdx.x;
  if (t < 128) {
    float a, b;
    bn_from_stats(stIn, gIn, beIn, t, a, b);
    sc_s[t] = a; sh_s[t] = b;
  }
  __syncthreads();
  const int r0 = gstart[g], r1 = gstart[g + 1];
  const int q = t & 15;
  const int rr = t >> 4;
  const int c0 = q * 8;
  float sc[8], sh[8], acc[8];
  #pragma unroll
  for (int i = 0; i < 8; ++i) { sc[i] = sc_s[c0 + i]; sh[i] = sh_s[c0 + i]; acc[i] = 0.f; }
  for (int r = r0 + rr; r < r1; r += 16) {
    const uint4 v = ((const uint4*)Z)[(size_t)r * 16 + q];
    float o[8];
    o[0] = b2f_lo(v.x); o[1] = b2f_hi(v.x); o[2] = b2f_lo(v.y); o[3] = b2f_hi(v.y);
    o[4] = b2f_lo(v.z); o[5] = b2f_hi(v.z); o[6] = b2f_lo(v.w); o[7] = b2f_hi(v.w);
    #pragma unroll
    for (int i = 0; i < 8; ++i) {
      o[i] = fmaxf(fmaf(o[i], sc[i], sh[i]), 0.f);
      acc[i] += o[i];
    }
    if (WRITE_H) {
      uint4 ov;
      ov.x = pack2(o[0], o[1]); ov.y = pack2(o[2], o[3]);
      ov.z = pack2(o[4], o[5]); ov.w = pack2(o[6], o[7]);
      ((uint4*)h)[(size_t)r * 16 + q] = ov;
    }
  }
  #pragma unroll
  for (int i = 0; i < 8; ++i) red[t * 8 + i] = acc[i];
  __syncthreads();
  for (int off = 8; off >= 1; off >>= 1) {
    if (rr < off) {
      #pragma unroll
      for (int i = 0; i < 8; ++i)
        red[t * 8 + i] += red[(t + off * 16) * 8 + i];
    }
    __syncthreads();
  }
  // red[0..127] now holds this layer's pooled sums (index = channel)
  if (!FINAL) {
    if (rr == 0) {
      #pragma unroll
      for (int i = 0; i < 8; ++i)
        pooled[(size_t)g * 256 + layerOff + c0 + i] = red[t * 8 + i];
    }
  } else {
    float part = 0.f;
    if (t < 128)
      part = pooled[(size_t)g * 256 + t] * jkw[t] + red[t] * jkw[128 + t];
    red[1024 + t] = part;
    __syncthreads();
    for (int off = 64; off >= 1; off >>= 1) {
      if (t < off) red[1024 + t] += red[1024 + t + off];
      __syncthreads();
    }
    if (t == 0)
      out[g] = red[1024] / fmaxf(counts[g], 1.f) + jkb[0];
  }
}

// ---------------------------------------------------------------------------
extern "C" void kernel_launch(void* const* d_in, const int* in_sizes, int n_in,
                              void* d_out, int out_size, void* d_ws,
                              size_t ws_size, hipStream_t stream) {
  const float* x     = (const float*)d_in[0];
  const int*   ei    = (const int*)d_in[1];
  const int*   batch = (const int*)d_in[2];
  const float* lin_w = (const float*)d_in[3];
  const float* lin_b = (const float*)d_in[4];
  const float* w1    = (const float*)d_in[5];
  const float* b1    = (const float*)d_in[6];
  const float* g1    = (const float*)d_in[7];
  const float* be1   = (const float*)d_in[8];
  const float* w2    = (const float*)d_in[9];
  const float* b2    = (const float*)d_in[10];
  const float* g2    = (const float*)d_in[11];
  const float* be2   = (const float*)d_in[12];
  const float* jkw   = (const float*)d_in[13];
  const float* jkb   = (const float*)d_in[14];
  float* out = (float*)d_out;

  char* base = (char*)d_ws;
  unsigned short* hb  = (unsigned short*)base;                 // NN*128 bf16 (buffer A)
  unsigned short* agb = hb + (size_t)NN * 128;                 // NN*128 bf16 (buffer B)
  unsigned short* WtA = agb + (size_t)NN * 128;                // 5*16384 bf16
  float* pooled = (float*)(WtA + 5 * 16384);                   // NG*256
  float* counts = pooled + (size_t)NG * 256;                   // NG
  int* gstart = (int*)(counts + NG);                           // NG+1 (+pad)
  int* rowptr = gstart + NG + 4;                               // NN+1 (+pad)
  int* bsum   = rowptr + NN + 4;                               // 196 (+pad)
  int* boff   = bsum + 200;                                    // 196 (+pad)
  int* pck    = boff + 200;                                    // NE
  int* cnt    = pck + NE;                                      // NN   (zeroed)
  float* stats = (float*)(cnt + NN);                           // 4*4096 (zeroed)
  // stats set s (0..3): psum = stats + s*4096, psq = psum + 2048

  setup_k<<<583, 256, 0, stream>>>(lin_w, w1, w2, WtA, batch, gstart, counts,
                                   cnt, stats);

  // CSR build (by dst)
  edge_hist<<<(NE + 255) / 256, 256, 0, stream>>>(ei, cnt);
  scan1<<<SCAN_B, 256, 0, stream>>>(cnt, rowptr, bsum);
  scan2<<<1, 256, 0, stream>>>(bsum, boff, rowptr + NN);
  scan3<<<SCAN_B, 256, 0, stream>>>(rowptr, boff, cnt);
  build_csr<<<(NE + 255) / 256, 256, 0, stream>>>(ei, cnt, pck);

  const int gemm_grid = (NN + 63) / 64;      // 782
  const int gath_grid = (NN + 31) / 32;      // 1563

  float* st1_0 = stats;
  float* st2_0 = stats + 4096;
  float* st1_1 = stats + 2 * 4096;
  float* st2_1 = stats + 3 * 4096;

  // h0 = x @ lin_w + lin_b  (fp32 input read directly) -> A
  gemm_fused<3, false><<<gemm_grid, 256, 0, stream>>>(
      x, nullptr, nullptr, nullptr, WtA, lin_b, hb, nullptr, nullptr, NN);

  // ---- layer 0 ----
  gemm_gather32<<<gath_grid, 256, 0, stream>>>(
      hb, rowptr, pck, WtA + 1 * 16384, b1, agb, st1_0, st1_0 + 2048, NN);
  gemm_fused<2, true><<<gemm_grid, 256, 0, stream>>>(
      agb, st1_0, g1, be1, WtA + 3 * 16384, b2, agb, st2_0, st2_0 + 2048, NN);
  // pool layer 0 + write h1 = relu(bn(z2)) into A (h0 is dead)
  bn_relu_pool_seg_b<true, false><<<NG, 256, 0, stream>>>(
      agb, st2_0, g2, be2, gstart, hb, pooled, 0,
      nullptr, nullptr, nullptr, nullptr);

  // ---- layer 1 ----
  gemm_gather32<<<gath_grid, 256, 0, stream>>>(
      hb, rowptr, pck, WtA + 2 * 16384, b1 + 128, agb, st1_1, st1_1 + 2048, NN);
  gemm_fused<2, true><<<gemm_grid, 256, 0, stream>>>(
      agb, st1_1, g1 + 128, be1 + 128, WtA + 4 * 16384, b2 + 128, agb,
      st2_1, st2_1 + 2048, NN);
  // pool layer 1 + final projection (emits out directly)
  bn_relu_pool_seg_b<false, true><<<NG, 256, 0, stream>>>(
      agb, st2_1, g2 + 128, be2 + 128, gstart, nullptr, pooled, 128,
      counts, jkw, jkb, out);
}

// Round 12
// 238.239 us; speedup vs baseline: 4.7312x; 1.0082x over previous
//
#include <hip/hip_runtime.h>
#include <cstddef>

#define NN 50000
#define NE 640000
#define NG 512
#define NL 2
#define NSLOT 16
#define SCAN_B 196
#define G3_BLKS 782
constexpr float BN_EPS = 1e-5f;

typedef __attribute__((ext_vector_type(8))) short bf16x8;
typedef __attribute__((ext_vector_type(16))) float f32x16;

__device__ inline float b2f_lo(unsigned int u) {
  union { unsigned int i; float f; } v; v.i = u << 16; return v.f;
}
__device__ inline float b2f_hi(unsigned int u) {
  union { unsigned int i; float f; } v; v.i = u & 0xffff0000u; return v.f;
}
__device__ inline unsigned short f2b(float f) {
  union { float f; unsigned int i; } v; v.f = f;
  return (unsigned short)((v.i + 0x7fffu + ((v.i >> 16) & 1u)) >> 16);
}
__device__ inline unsigned int pack2(float lo, float hi) {
  return (unsigned int)f2b(lo) | ((unsigned int)f2b(hi) << 16);
}
// swizzled LDS byte offset for [row][256B]; bijective per row (XORs bits 4-7)
__device__ inline int swz(int row, int b) { return row * 256 + (b ^ ((row & 15) << 4)); }

__device__ inline void unpack_add(const uint4 v, float* a) {
  a[0] += b2f_lo(v.x); a[1] += b2f_hi(v.x); a[2] += b2f_lo(v.y); a[3] += b2f_hi(v.y);
  a[4] += b2f_lo(v.z); a[5] += b2f_hi(v.z); a[6] += b2f_lo(v.w); a[7] += b2f_hi(v.w);
}

// Inline BN finalize from raw 16-slot partials (psum at st, psq at st+2048)
__device__ inline void bn_from_stats(const float* __restrict__ st,
                                     const float* __restrict__ gamma,
                                     const float* __restrict__ beta, int c,
                                     float& sc, float& sh) {
  float s = 0.f, s2 = 0.f;
  #pragma unroll
  for (int b = 0; b < NSLOT; ++b) {
    s += st[b * 128 + c];
    s2 += st[2048 + b * 128 + c];
  }
  const float inv_n = 1.f / (float)NN;
  const float mu = s * inv_n;
  const float var = fmaxf(s2 * inv_n - mu * mu, 0.f);
  sc = rsqrtf(var + BN_EPS) * gamma[c];
  sh = beta[c] - mu * sc;
}

// ---------------------------------------------------------------------------
// Gather-fused MFMA GEMM, 32-row tile (proven row-parallel form, UNCHANGED):
// C = (gather(h)) @ W + bias, with fused column stats.
// ---------------------------------------------------------------------------
__global__ __launch_bounds__(256) void gemm_gather32(
    const unsigned short* __restrict__ h, const int* __restrict__ rowptr,
    const int* __restrict__ pck, const unsigned short* __restrict__ Wt,
    const float* __restrict__ bias, unsigned short* __restrict__ C,
    float* __restrict__ psum, float* __restrict__ psq, int n) {
  __shared__ uint4 Au[16][32];  // [k-chunk][row], 8 KB
  __shared__ float colsum[128];
  __shared__ float colsq[128];
  const int t = threadIdx.x;
  const int row0 = blockIdx.x * 32;

  if (t < 128) { colsum[t] = 0.f; colsq[t] = 0.f; }

  const int ln = t & 31;   // row
  const int cg = t >> 5;   // 0..7 -> chunks cg*2, cg*2+1
  const int gr = row0 + ln;
  const uint4* h4 = (const uint4*)h;
  float a0[8], a1[8];
  #pragma unroll
  for (int p = 0; p < 8; ++p) { a0[p] = 0.f; a1[p] = 0.f; }
  if (gr < n) {
    {
      const uint4* p = &h4[(size_t)gr * 16 + cg * 2];
      unpack_add(p[0], a0); unpack_add(p[1], a1);
    }
    const int beg = rowptr[gr], end = rowptr[gr + 1];
    int j = beg;
    for (; j + 1 < end; j += 2) {
      const int s0i = pck[j] & 0x01FFFFFF;
      const int s1i = pck[j + 1] & 0x01FFFFFF;
      const uint4* p0 = &h4[(size_t)s0i * 16 + cg * 2];
      const uint4* p1 = &h4[(size_t)s1i * 16 + cg * 2];
      const uint4 v00 = p0[0], v01 = p0[1];
      const uint4 v10 = p1[0], v11 = p1[1];
      unpack_add(v00, a0); unpack_add(v01, a1);
      unpack_add(v10, a0); unpack_add(v11, a1);
    }
    if (j < end) {
      const int s0i = pck[j] & 0x01FFFFFF;
      const uint4* p0 = &h4[(size_t)s0i * 16 + cg * 2];
      unpack_add(p0[0], a0); unpack_add(p0[1], a1);
    }
  }
  {
    uint4 o0, o1;
    o0.x = pack2(a0[0], a0[1]); o0.y = pack2(a0[2], a0[3]);
    o0.z = pack2(a0[4], a0[5]); o0.w = pack2(a0[6], a0[7]);
    o1.x = pack2(a1[0], a1[1]); o1.y = pack2(a1[2], a1[3]);
    o1.z = pack2(a1[4], a1[5]); o1.w = pack2(a1[6], a1[7]);
    Au[cg * 2][ln] = o0;
    Au[cg * 2 + 1][ln] = o1;
  }
  __syncthreads();

  const int w = t >> 6;
  const int l = t & 63;
  const int lane31 = l & 31;
  const int khalf = l >> 5;

  f32x16 acc;
  #pragma unroll
  for (int i = 0; i < 16; ++i) acc[i] = 0.f;

  const unsigned short* Bp = Wt + (size_t)(w * 32 + lane31) * 128 + 8 * khalf;
  #pragma unroll
  for (int k0 = 0; k0 < 8; ++k0) {
    const bf16x8 aF = *(const bf16x8*)&Au[k0 * 2 + khalf][lane31];
    const bf16x8 bF = *(const bf16x8*)(Bp + k0 * 16);
    acc = __builtin_amdgcn_mfma_f32_32x32x16_bf16(aF, bF, acc, 0, 0, 0);
  }

  const int col = w * 32 + lane31;
  const float bs = bias[col];
  float s0 = 0.f, q0 = 0.f;
  #pragma unroll
  for (int r = 0; r < 16; ++r) {
    const int row = (r & 3) + 8 * (r >> 2) + 4 * khalf;
    const int grow = row0 + row;
    if (grow < n) {
      const float v = acc[r] + bs;
      C[(size_t)grow * 128 + col] = f2b(v);
      s0 += v; q0 = fmaf(v, v, q0);
    }
  }
  atomicAdd(&colsum[col], s0);
  atomicAdd(&colsq[col], q0);
  __syncthreads();
  if (t < 128) {
    const int slot = blockIdx.x & (NSLOT - 1);
    atomicAdd(&psum[slot * 128 + t], colsum[t]);
    atomicAdd(&psq[slot * 128 + t], colsq[t]);
  }
}

// ---------------------------------------------------------------------------
// BN-GEMM (64-row tile): C = relu(bn(A)) @ W + bias (in-place safe), stats.
// BN scale/shift derived inline from raw stIn. Packed epilogue via Al.
// ---------------------------------------------------------------------------
__global__ __launch_bounds__(256) void gemm_bn(
    const unsigned short* __restrict__ Ain, const float* __restrict__ stIn,
    const float* __restrict__ gIn, const float* __restrict__ beIn,
    const unsigned short* __restrict__ Wt, const float* __restrict__ bias,
    unsigned short* __restrict__ C, float* __restrict__ psum,
    float* __restrict__ psq, int n) {
  __shared__ char Al[16384];
  __shared__ float colsum[128];
  __shared__ float colsq[128];
  __shared__ float sc_s[128], sh_s[128];
  const int t = threadIdx.x;
  const int row0 = blockIdx.x * 64;

  if (t < 128) {
    colsum[t] = 0.f; colsq[t] = 0.f;
    float a, b;
    bn_from_stats(stIn, gIn, beIn, t, a, b);
    sc_s[t] = a; sh_s[t] = b;
  }
  __syncthreads();

  #pragma unroll
  for (int ii = 0; ii < 4; ++ii) {
    const int i = t + ii * 256;
    const int r = i >> 4;
    const int u = (i & 15) << 4;
    const int gr = row0 + r;
    uint4 v = make_uint4(0u, 0u, 0u, 0u);
    if (gr < n) {
      v = *(const uint4*)((const char*)Ain + (size_t)gr * 256 + u);
      const int c0 = u >> 1;
      unsigned int pw[4] = {v.x, v.y, v.z, v.w};
      #pragma unroll
      for (int p = 0; p < 4; ++p) {
        float lo = b2f_lo(pw[p]);
        float hi = b2f_hi(pw[p]);
        lo = fmaxf(fmaf(lo, sc_s[c0 + 2 * p], sh_s[c0 + 2 * p]), 0.f);
        hi = fmaxf(fmaf(hi, sc_s[c0 + 2 * p + 1], sh_s[c0 + 2 * p + 1]), 0.f);
        pw[p] = pack2(lo, hi);
      }
      v = make_uint4(pw[0], pw[1], pw[2], pw[3]);
    }
    *(uint4*)(Al + swz(r, u)) = v;
  }
  __syncthreads();

  const int w = t >> 6;
  const int l = t & 63;
  const int lane31 = l & 31;
  const int khalf = l >> 5;
  const int mrow = (w & 1) * 32;
  const int c0 = (w >> 1) * 64;

  f32x16 acc0, acc1;
  #pragma unroll
  for (int i = 0; i < 16; ++i) { acc0[i] = 0.f; acc1[i] = 0.f; }

  const unsigned short* Bp0 = Wt + (size_t)(c0 + lane31) * 128 + 8 * khalf;
  const unsigned short* Bp1 = Wt + (size_t)(c0 + 32 + lane31) * 128 + 8 * khalf;

  #pragma unroll
  for (int k0 = 0; k0 < 128; k0 += 16) {
    const int kb = (k0 + 8 * khalf) * 2;
    const bf16x8 a  = *(const bf16x8*)(Al + swz(mrow + lane31, kb));
    const bf16x8 b0 = *(const bf16x8*)(Bp0 + k0);
    const bf16x8 b1 = *(const bf16x8*)(Bp1 + k0);
    acc0 = __builtin_amdgcn_mfma_f32_32x32x16_bf16(a, b0, acc0, 0, 0, 0);
    acc1 = __builtin_amdgcn_mfma_f32_32x32x16_bf16(a, b1, acc1, 0, 0, 0);
  }
  __syncthreads();  // all k-loop reads of Al done; Al now reused as C tile

  const float bias0 = bias[c0 + lane31];
  const float bias1 = bias[c0 + 32 + lane31];
  float s0 = 0.f, q0 = 0.f, s1 = 0.f, q1 = 0.f;
  #pragma unroll
  for (int r = 0; r < 16; ++r) {
    const int row = mrow + (r & 3) + 8 * (r >> 2) + 4 * khalf;
    const float v0 = acc0[r] + bias0;
    const float v1 = acc1[r] + bias1;
    *(unsigned short*)(Al + swz(row, (c0 + lane31) * 2)) = f2b(v0);
    *(unsigned short*)(Al + swz(row, (c0 + 32 + lane31) * 2)) = f2b(v1);
    if (row0 + row < n) {
      s0 += v0; q0 = fmaf(v0, v0, q0);
      s1 += v1; q1 = fmaf(v1, v1, q1);
    }
  }
  atomicAdd(&colsum[c0 + lane31], s0);
  atomicAdd(&colsq[c0 + lane31], q0);
  atomicAdd(&colsum[c0 + 32 + lane31], s1);
  atomicAdd(&colsq[c0 + 32 + lane31], q1);
  __syncthreads();

  // coalesced copy-out: 16 threads per row, uint4 each
  #pragma unroll
  for (int ii = 0; ii < 4; ++ii) {
    const int i = t + ii * 256;
    const int r = i >> 4;
    const int u = (i & 15) << 4;
    const int gr = row0 + r;
    if (gr < n)
      *(uint4*)((char*)C + (size_t)gr * 256 + u) = *(const uint4*)(Al + swz(r, u));
  }
  if (t < 128) {
    const int slot = blockIdx.x & (NSLOT - 1);
    atomicAdd(&psum[slot * 128 + t], colsum[t]);
    atomicAdd(&psq[slot * 128 + t], colsq[t]);
  }
}

// ---------------------------------------------------------------------------
// Merged: h0 GEMM (fp32 x -> bf16) for blocks < G3_BLKS; CSR bucket fill for
// the rest (independent work, overlapped in one dispatch).
// ---------------------------------------------------------------------------
__global__ __launch_bounds__(256) void gemm3_build(
    const float* __restrict__ x, const unsigned short* __restrict__ Wt,
    const float* __restrict__ bias, unsigned short* __restrict__ C,
    const int* __restrict__ ei, int* __restrict__ cursor,
    int* __restrict__ pck, int n) {
  __shared__ char Al[16384];
  const int t = threadIdx.x;
  if (blockIdx.x >= G3_BLKS) {
    const int e = (blockIdx.x - G3_BLKS) * 256 + t;
    if (e < NE) {
      const int src = ei[e];
      const int dst = ei[NE + e];
      const int pos = atomicAdd(&cursor[dst], 1);
      pck[pos] = src | ((dst & 31) << 25);
    }
    return;
  }
  const int row0 = blockIdx.x * 64;

  #pragma unroll
  for (int ii = 0; ii < 4; ++ii) {
    const int i = t + ii * 256;
    const int r = i >> 4;
    const int u = (i & 15) << 4;
    const int gr = row0 + r;
    uint4 v = make_uint4(0u, 0u, 0u, 0u);
    if (gr < n) {
      const float4 f0 = *(const float4*)(x + (size_t)gr * 128 + (u >> 1));
      const float4 f1 = *(const float4*)(x + (size_t)gr * 128 + (u >> 1) + 4);
      v.x = pack2(f0.x, f0.y); v.y = pack2(f0.z, f0.w);
      v.z = pack2(f1.x, f1.y); v.w = pack2(f1.z, f1.w);
    }
    *(uint4*)(Al + swz(r, u)) = v;
  }
  __syncthreads();

  const int w = t >> 6;
  const int l = t & 63;
  const int lane31 = l & 31;
  const int khalf = l >> 5;
  const int mrow = (w & 1) * 32;
  const int c0 = (w >> 1) * 64;

  f32x16 acc0, acc1;
  #pragma unroll
  for (int i = 0; i < 16; ++i) { acc0[i] = 0.f; acc1[i] = 0.f; }

  const unsigned short* Bp0 = Wt + (size_t)(c0 + lane31) * 128 + 8 * khalf;
  const unsigned short* Bp1 = Wt + (size_t)(c0 + 32 + lane31) * 128 + 8 * khalf;

  #pragma unroll
  for (int k0 = 0; k0 < 128; k0 += 16) {
    const int kb = (k0 + 8 * khalf) * 2;
    const bf16x8 a  = *(const bf16x8*)(Al + swz(mrow + lane31, kb));
    const bf16x8 b0 = *(const bf16x8*)(Bp0 + k0);
    const bf16x8 b1 = *(const bf16x8*)(Bp1 + k0);
    acc0 = __builtin_amdgcn_mfma_f32_32x32x16_bf16(a, b0, acc0, 0, 0, 0);
    acc1 = __builtin_amdgcn_mfma_f32_32x32x16_bf16(a, b1, acc1, 0, 0, 0);
  }
  __syncthreads();

  const float bias0 = bias[c0 + lane31];
  const float bias1 = bias[c0 + 32 + lane31];
  #pragma unroll
  for (int r = 0; r < 16; ++r) {
    const int row = mrow + (r & 3) + 8 * (r >> 2) + 4 * khalf;
    *(unsigned short*)(Al + swz(row, (c0 + lane31) * 2)) = f2b(acc0[r] + bias0);
    *(unsigned short*)(Al + swz(row, (c0 + 32 + lane31) * 2)) = f2b(acc1[r] + bias1);
  }
  __syncthreads();
  #pragma unroll
  for (int ii = 0; ii < 4; ++ii) {
    const int i = t + ii * 256;
    const int r = i >> 4;
    const int u = (i & 15) << 4;
    const int gr = row0 + r;
    if (gr < n)
      *(uint4*)((char*)C + (size_t)gr * 256 + u) = *(const uint4*)(Al + swz(r, u));
  }
}

// ---------------------------------------------------------------------------
// Fused setup: weight conversion + cnt/stats zero + graph segment search
// ---------------------------------------------------------------------------
__global__ __launch_bounds__(256) void setup_k(
    const float* __restrict__ lw, const float* __restrict__ w1,
    const float* __restrict__ w2, unsigned short* __restrict__ Wt,
    const int* __restrict__ batch, int* __restrict__ gstart,
    float* __restrict__ counts, int* __restrict__ cnt,
    float* __restrict__ stats) {
  const int b = blockIdx.x, t = threadIdx.x;
  if (b < 320) {  // weight convert (5*16384)
    const int i = b * 256 + t;
    const int m = i >> 14, r = i & 16383;
    const int ncol = r >> 7, k = r & 127;
    const float* src = (m == 0) ? lw : (m <= 2) ? (w1 + (m - 1) * 16384)
                                                : (w2 + (m - 3) * 16384);
    Wt[i] = f2b(src[k * 128 + ncol]);
  } else if (b < 516) {  // zero cnt (50000)
    const int i = (b - 320) * 256 + t;
    if (i < NN) cnt[i] = 0;
  } else if (b < 580) {  // zero stats (4*4096)
    stats[(b - 516) * 256 + t] = 0.f;
  } else {  // segments (NG+1)
    const int g = (b - 580) * 256 + t;
    if (g > NG) return;
    int lo = 0, hi = NN;
    while (lo < hi) { int m = (lo + hi) >> 1; if (batch[m] < g) lo = m + 1; else hi = m; }
    gstart[g] = lo;
    if (g < NG) {
      int lo1 = lo, hi1 = NN;
      while (lo1 < hi1) { int m = (lo1 + hi1) >> 1; if (batch[m] < g + 1) lo1 = m + 1; else hi1 = m; }
      counts[g] = (float)(lo1 - lo);
    }
  }
}

// ---------------------------------------------------------------------------
// CSR build: histogram -> scan1 (per-block) -> scan23 (offsets + cursor)
// ---------------------------------------------------------------------------
__global__ __launch_bounds__(256) void edge_hist(const int* __restrict__ ei,
                                                 int* __restrict__ cnt) {
  const int e = blockIdx.x * 256 + threadIdx.x;
  if (e >= NE) return;
  atomicAdd(&cnt[ei[NE + e]], 1);
}

__global__ __launch_bounds__(256) void scan1(const int* __restrict__ cnt,
                                             int* __restrict__ rowptr,
                                             int* __restrict__ bsum) {
  __shared__ int s[256];
  const int b = blockIdx.x, t = threadIdx.x;
  const int i = b * 256 + t;
  const int v = (i < NN) ? cnt[i] : 0;
  s[t] = v;
  __syncthreads();
  for (int off = 1; off < 256; off <<= 1) {
    const int x = (t >= off) ? s[t - off] : 0;
    __syncthreads();
    s[t] += x;
    __syncthreads();
  }
  if (i < NN) rowptr[i] = s[t] - v;
  if (t == 255) bsum[b] = s[255];
}

// scan2+scan3 fused: every block recomputes the 196-entry block prefix
__global__ __launch_bounds__(256) void scan23(int* __restrict__ rowptr,
                                              const int* __restrict__ bsum,
                                              int* __restrict__ cursor) {
  __shared__ int s[256];
  const int blk = blockIdx.x, t = threadIdx.x;
  const int v = (t < SCAN_B) ? bsum[t] : 0;
  s[t] = v;
  __syncthreads();
  for (int off = 1; off < 256; off <<= 1) {
    const int x = (t >= off) ? s[t - off] : 0;
    __syncthreads();
    s[t] += x;
    __syncthreads();
  }
  const int boff = s[blk] - bsum[blk];  // exclusive prefix for this block
  const int i = blk * 256 + t;
  if (i < NN) {
    const int r = rowptr[i] + boff;
    rowptr[i] = r;
    cursor[i] = r;
  }
  if (blk == SCAN_B - 1 && t == 0) rowptr[NN] = s[255];
}

// ---------------------------------------------------------------------------
// Per-graph fused BN+ReLU+mean-pool (bf16 in); BN derived inline.
// WRITE_H: writes h = relu(bn(Z)) for next layer. FINAL: emits out[g].
// ---------------------------------------------------------------------------
template <bool WRITE_H, bool FINAL>
__global__ __launch_bounds__(256) void bn_relu_pool_seg_b(
    const unsigned short* __restrict__ Z, const float* __restrict__ stIn,
    const float* __restrict__ gIn, const float* __restrict__ beIn,
    const int* __restrict__ gstart, unsigned short* __restrict__ h,
    float* __restrict__ pooled, int layerOff,
    const float* __restrict__ counts, const float* __restrict__ jkw,
    const float* __restrict__ jkb, float* __restrict__ out) {
  __shared__ float sc_s[128], sh_s[128];
  __shared__ float red[256 * 8];
  const int g = blockIdx.x;
  const int t = threadIdx.x;
  if (t < 128) {
    float a, b;
    bn_from_stats(stIn, gIn, beIn, t, a, b);
    sc_s[t] = a; sh_s[t] = b;
  }
  __syncthreads();
  const int r0 = gstart[g], r1 = gstart[g + 1];
  const int q = t & 15;
  const int rr = t >> 4;
  const int c0 = q * 8;
  float sc[8], sh[8], acc[8];
  #pragma unroll
  for (int i = 0; i < 8; ++i) { sc[i] = sc_s[c0 + i]; sh[i] = sh_s[c0 + i]; acc[i] = 0.f; }
  for (int r = r0 + rr; r < r1; r += 16) {
    const uint4 v = ((const uint4*)Z)[(size_t)r * 16 + q];
    float o[8];
    o[0] = b2f_lo(v.x); o[1] = b2f_hi(v.x); o[2] = b2f_lo(v.y); o[3] = b2f_hi(v.y);
    o[4] = b2f_lo(v.z); o[5] = b2f_hi(v.z); o[6] = b2f_lo(v.w); o[7] = b2f_hi(v.w);
    #pragma unroll
    for (int i = 0; i < 8; ++i) {
      o[i] = fmaxf(fmaf(o[i], sc[i], sh[i]), 0.f);
      acc[i] += o[i];
    }
    if (WRITE_H) {
      uint4 ov;
      ov.x = pack2(o[0], o[1]); ov.y = pack2(o[2], o[3]);
      ov.z = pack2(o[4], o[5]); ov.w = pack2(o[6], o[7]);
      ((uint4*)h)[(size_t)r * 16 + q] = ov;
    }
  }
  #pragma unroll
  for (int i = 0; i < 8; ++i) red[t * 8 + i] = acc[i];
  __syncthreads();
  for (int off = 8; off >= 1; off >>= 1) {
    if (rr < off) {
      #pragma unroll
      for (int i = 0; i < 8; ++i)
        red[t * 8 + i] += red[(t + off * 16) * 8 + i];
    }
    __syncthreads();
  }
  if (!FINAL) {
    if (rr == 0) {
      #pragma unroll
      for (int i = 0; i < 8; ++i)
        pooled[(size_t)g * 256 + layerOff + c0 + i] = red[t * 8 + i];
    }
  } else {
    float part = 0.f;
    if (t < 128)
      part = pooled[(size_t)g * 256 + t] * jkw[t] + red[t] * jkw[128 + t];
    red[1024 + t] = part;
    __syncthreads();
    for (int off = 64; off >= 1; off >>= 1) {
      if (t < off) red[1024 + t] += red[1024 + t + off];
      __syncthreads();
    }
    if (t == 0)
      out[g] = red[1024] / fmaxf(counts[g], 1.f) + jkb[0];
  }
}

// ---------------------------------------------------------------------------
extern "C" void kernel_launch(void* const* d_in, const int* in_sizes, int n_in,
                              void* d_out, int out_size, void* d_ws,
                              size_t ws_size, hipStream_t stream) {
  const float* x     = (const float*)d_in[0];
  const int*   ei    = (const int*)d_in[1];
  const int*   batch = (const int*)d_in[2];
  const float* lin_w = (const float*)d_in[3];
  const float* lin_b = (const float*)d_in[4];
  const float* w1    = (const float*)d_in[5];
  const float* b1    = (const float*)d_in[6];
  const float* g1    = (const float*)d_in[7];
  const float* be1   = (const float*)d_in[8];
  const float* w2    = (const float*)d_in[9];
  const float* b2    = (const float*)d_in[10];
  const float* g2    = (const float*)d_in[11];
  const float* be2   = (const float*)d_in[12];
  const float* jkw   = (const float*)d_in[13];
  const float* jkb   = (const float*)d_in[14];
  float* out = (float*)d_out;

  char* base = (char*)d_ws;
  unsigned short* hb  = (unsigned short*)base;                 // NN*128 bf16 (A)
  unsigned short* agb = hb + (size_t)NN * 128;                 // NN*128 bf16 (B)
  unsigned short* WtA = agb + (size_t)NN * 128;                // 5*16384 bf16
  float* pooled = (float*)(WtA + 5 * 16384);                   // NG*256
  float* counts = pooled + (size_t)NG * 256;                   // NG
  int* gstart = (int*)(counts + NG);                           // NG+1 (+pad)
  int* rowptr = gstart + NG + 4;                               // NN+1 (+pad)
  int* bsum   = rowptr + NN + 4;                               // 196 (+pad)
  int* pck    = bsum + 200;                                    // NE
  int* cnt    = pck + NE;                                      // NN   (zeroed)
  float* stats = (float*)(cnt + NN);                           // 4*4096 (zeroed)
  // stats set s (0..3): psum = stats + s*4096, psq = psum + 2048

  setup_k<<<583, 256, 0, stream>>>(lin_w, w1, w2, WtA, batch, gstart, counts,
                                   cnt, stats);

  edge_hist<<<(NE + 255) / 256, 256, 0, stream>>>(ei, cnt);
  scan1<<<SCAN_B, 256, 0, stream>>>(cnt, rowptr, bsum);
  scan23<<<SCAN_B, 256, 0, stream>>>(rowptr, bsum, cnt);

  // h0 GEMM (782 blocks) overlapped with CSR bucket fill (2500 blocks)
  gemm3_build<<<G3_BLKS + (NE + 255) / 256, 256, 0, stream>>>(
      x, WtA, lin_b, hb, ei, cnt, pck, NN);

  const int gemm_grid = (NN + 63) / 64;      // 782
  const int gath_grid = (NN + 31) / 32;      // 1563

  float* st1_0 = stats;
  float* st2_0 = stats + 4096;
  float* st1_1 = stats + 2 * 4096;
  float* st2_1 = stats + 3 * 4096;

  // ---- layer 0 ----
  gemm_gather32<<<gath_grid, 256, 0, stream>>>(
      hb, rowptr, pck, WtA + 1 * 16384, b1, agb, st1_0, st1_0 + 2048, NN);
  gemm_bn<<<gemm_grid, 256, 0, stream>>>(
      agb, st1_0, g1, be1, WtA + 3 * 16384, b2, agb, st2_0, st2_0 + 2048, NN);
  bn_relu_pool_seg_b<true, false><<<NG, 256, 0, stream>>>(
      agb, st2_0, g2, be2, gstart, hb, pooled, 0,
      nullptr, nullptr, nullptr, nullptr);

  // ---- layer 1 ----
  gemm_gather32<<<gath_grid, 256, 0, stream>>>(
      hb, rowptr, pck, WtA + 2 * 16384, b1 + 128, agb, st1_1, st1_1 + 2048, NN);
  gemm_bn<<<gemm_grid, 256, 0, stream>>>(
      agb, st1_1, g1 + 128, be1 + 128, WtA + 4 * 16384, b2 + 128, agb,
      st2_1, st2_1 + 2048, NN);
  bn_relu_pool_seg_b<false, true><<<NG, 256, 0, stream>>>(
      agb, st2_1, g2 + 128, be2 + 128, gstart, nullptr, pooled, 128,
      counts, jkw, jkb, out);
}

// Round 13
// 234.778 us; speedup vs baseline: 4.8009x; 1.0147x over previous
//
#include <hip/hip_runtime.h>
#include <cstddef>

#define NN 50000
#define NE 640000
#define NG 512
#define NL 2
#define NSLOT 16
#define SCAN_B 196
constexpr float BN_EPS = 1e-5f;

typedef __attribute__((ext_vector_type(8))) short bf16x8;
typedef __attribute__((ext_vector_type(16))) float f32x16;

__device__ inline float b2f_lo(unsigned int u) {
  union { unsigned int i; float f; } v; v.i = u << 16; return v.f;
}
__device__ inline float b2f_hi(unsigned int u) {
  union { unsigned int i; float f; } v; v.i = u & 0xffff0000u; return v.f;
}
__device__ inline unsigned short f2b(float f) {
  union { float f; unsigned int i; } v; v.f = f;
  return (unsigned short)((v.i + 0x7fffu + ((v.i >> 16) & 1u)) >> 16);
}
__device__ inline unsigned int pack2(float lo, float hi) {
  return (unsigned int)f2b(lo) | ((unsigned int)f2b(hi) << 16);
}
// swizzled LDS byte offset for [row][256B]; bijective per row (XORs bits 4-7)
__device__ inline int swz(int row, int b) { return row * 256 + (b ^ ((row & 15) << 4)); }

__device__ inline void unpack_add(const uint4 v, float* a) {
  a[0] += b2f_lo(v.x); a[1] += b2f_hi(v.x); a[2] += b2f_lo(v.y); a[3] += b2f_hi(v.y);
  a[4] += b2f_lo(v.z); a[5] += b2f_hi(v.z); a[6] += b2f_lo(v.w); a[7] += b2f_hi(v.w);
}

// Inline BN finalize from raw 16-slot partials (psum at st, psq at st+2048)
__device__ inline void bn_from_stats(const float* __restrict__ st,
                                     const float* __restrict__ gamma,
                                     const float* __restrict__ beta, int c,
                                     float& sc, float& sh) {
  float s = 0.f, s2 = 0.f;
  #pragma unroll
  for (int b = 0; b < NSLOT; ++b) {
    s += st[b * 128 + c];
    s2 += st[2048 + b * 128 + c];
  }
  const float inv_n = 1.f / (float)NN;
  const float mu = s * inv_n;
  const float var = fmaxf(s2 * inv_n - mu * mu, 0.f);
  sc = rsqrtf(var + BN_EPS) * gamma[c];
  sh = beta[c] - mu * sc;
}

// ---------------------------------------------------------------------------
// Gather-fused MFMA GEMM, 32-row tile (proven row-parallel form, UNCHANGED):
// C = (gather(h)) @ W + bias, with fused column stats.
// ---------------------------------------------------------------------------
__global__ __launch_bounds__(256) void gemm_gather32(
    const unsigned short* __restrict__ h, const int* __restrict__ rowptr,
    const int* __restrict__ pck, const unsigned short* __restrict__ Wt,
    const float* __restrict__ bias, unsigned short* __restrict__ C,
    float* __restrict__ psum, float* __restrict__ psq, int n) {
  __shared__ uint4 Au[16][32];  // [k-chunk][row], 8 KB
  __shared__ float colsum[128];
  __shared__ float colsq[128];
  const int t = threadIdx.x;
  const int row0 = blockIdx.x * 32;

  if (t < 128) { colsum[t] = 0.f; colsq[t] = 0.f; }

  const int ln = t & 31;   // row
  const int cg = t >> 5;   // 0..7 -> chunks cg*2, cg*2+1
  const int gr = row0 + ln;
  const uint4* h4 = (const uint4*)h;
  float a0[8], a1[8];
  #pragma unroll
  for (int p = 0; p < 8; ++p) { a0[p] = 0.f; a1[p] = 0.f; }
  if (gr < n) {
    {
      const uint4* p = &h4[(size_t)gr * 16 + cg * 2];
      unpack_add(p[0], a0); unpack_add(p[1], a1);
    }
    const int beg = rowptr[gr], end = rowptr[gr + 1];
    int j = beg;
    for (; j + 1 < end; j += 2) {
      const int s0i = pck[j] & 0x01FFFFFF;
      const int s1i = pck[j + 1] & 0x01FFFFFF;
      const uint4* p0 = &h4[(size_t)s0i * 16 + cg * 2];
      const uint4* p1 = &h4[(size_t)s1i * 16 + cg * 2];
      const uint4 v00 = p0[0], v01 = p0[1];
      const uint4 v10 = p1[0], v11 = p1[1];
      unpack_add(v00, a0); unpack_add(v01, a1);
      unpack_add(v10, a0); unpack_add(v11, a1);
    }
    if (j < end) {
      const int s0i = pck[j] & 0x01FFFFFF;
      const uint4* p0 = &h4[(size_t)s0i * 16 + cg * 2];
      unpack_add(p0[0], a0); unpack_add(p0[1], a1);
    }
  }
  {
    uint4 o0, o1;
    o0.x = pack2(a0[0], a0[1]); o0.y = pack2(a0[2], a0[3]);
    o0.z = pack2(a0[4], a0[5]); o0.w = pack2(a0[6], a0[7]);
    o1.x = pack2(a1[0], a1[1]); o1.y = pack2(a1[2], a1[3]);
    o1.z = pack2(a1[4], a1[5]); o1.w = pack2(a1[6], a1[7]);
    Au[cg * 2][ln] = o0;
    Au[cg * 2 + 1][ln] = o1;
  }
  __syncthreads();

  const int w = t >> 6;
  const int l = t & 63;
  const int lane31 = l & 31;
  const int khalf = l >> 5;

  f32x16 acc;
  #pragma unroll
  for (int i = 0; i < 16; ++i) acc[i] = 0.f;

  const unsigned short* Bp = Wt + (size_t)(w * 32 + lane31) * 128 + 8 * khalf;
  #pragma unroll
  for (int k0 = 0; k0 < 8; ++k0) {
    const bf16x8 aF = *(const bf16x8*)&Au[k0 * 2 + khalf][lane31];
    const bf16x8 bF = *(const bf16x8*)(Bp + k0 * 16);
    acc = __builtin_amdgcn_mfma_f32_32x32x16_bf16(aF, bF, acc, 0, 0, 0);
  }

  const int col = w * 32 + lane31;
  const float bs = bias[col];
  float s0 = 0.f, q0 = 0.f;
  #pragma unroll
  for (int r = 0; r < 16; ++r) {
    const int row = (r & 3) + 8 * (r >> 2) + 4 * khalf;
    const int grow = row0 + row;
    if (grow < n) {
      const float v = acc[r] + bs;
      C[(size_t)grow * 128 + col] = f2b(v);
      s0 += v; q0 = fmaf(v, v, q0);
    }
  }
  atomicAdd(&colsum[col], s0);
  atomicAdd(&colsq[col], q0);
  __syncthreads();
  if (t < 128) {
    const int slot = blockIdx.x & (NSLOT - 1);
    atomicAdd(&psum[slot * 128 + t], colsum[t]);
    atomicAdd(&psq[slot * 128 + t], colsq[t]);
  }
}

// ---------------------------------------------------------------------------
// BN-GEMM (64-row tile): C = relu(bn(A)) @ W + bias (in-place safe), stats.
// BN scale/shift derived inline from raw stIn. Packed epilogue via Al.
// ---------------------------------------------------------------------------
__global__ __launch_bounds__(256) void gemm_bn(
    const unsigned short* __restrict__ Ain, const float* __restrict__ stIn,
    const float* __restrict__ gIn, const float* __restrict__ beIn,
    const unsigned short* __restrict__ Wt, const float* __restrict__ bias,
    unsigned short* __restrict__ C, float* __restrict__ psum,
    float* __restrict__ psq, int n) {
  __shared__ char Al[16384];
  __shared__ float colsum[128];
  __shared__ float colsq[128];
  __shared__ float sc_s[128], sh_s[128];
  const int t = threadIdx.x;
  const int row0 = blockIdx.x * 64;

  if (t < 128) {
    colsum[t] = 0.f; colsq[t] = 0.f;
    float a, b;
    bn_from_stats(stIn, gIn, beIn, t, a, b);
    sc_s[t] = a; sh_s[t] = b;
  }
  __syncthreads();

  #pragma unroll
  for (int ii = 0; ii < 4; ++ii) {
    const int i = t + ii * 256;
    const int r = i >> 4;
    const int u = (i & 15) << 4;
    const int gr = row0 + r;
    uint4 v = make_uint4(0u, 0u, 0u, 0u);
    if (gr < n) {
      v = *(const uint4*)((const char*)Ain + (size_t)gr * 256 + u);
      const int c0 = u >> 1;
      unsigned int pw[4] = {v.x, v.y, v.z, v.w};
      #pragma unroll
      for (int p = 0; p < 4; ++p) {
        float lo = b2f_lo(pw[p]);
        float hi = b2f_hi(pw[p]);
        lo = fmaxf(fmaf(lo, sc_s[c0 + 2 * p], sh_s[c0 + 2 * p]), 0.f);
        hi = fmaxf(fmaf(hi, sc_s[c0 + 2 * p + 1], sh_s[c0 + 2 * p + 1]), 0.f);
        pw[p] = pack2(lo, hi);
      }
      v = make_uint4(pw[0], pw[1], pw[2], pw[3]);
    }
    *(uint4*)(Al + swz(r, u)) = v;
  }
  __syncthreads();

  const int w = t >> 6;
  const int l = t & 63;
  const int lane31 = l & 31;
  const int khalf = l >> 5;
  const int mrow = (w & 1) * 32;
  const int c0 = (w >> 1) * 64;

  f32x16 acc0, acc1;
  #pragma unroll
  for (int i = 0; i < 16; ++i) { acc0[i] = 0.f; acc1[i] = 0.f; }

  const unsigned short* Bp0 = Wt + (size_t)(c0 + lane31) * 128 + 8 * khalf;
  const unsigned short* Bp1 = Wt + (size_t)(c0 + 32 + lane31) * 128 + 8 * khalf;

  #pragma unroll
  for (int k0 = 0; k0 < 128; k0 += 16) {
    const int kb = (k0 + 8 * khalf) * 2;
    const bf16x8 a  = *(const bf16x8*)(Al + swz(mrow + lane31, kb));
    const bf16x8 b0 = *(const bf16x8*)(Bp0 + k0);
    const bf16x8 b1 = *(const bf16x8*)(Bp1 + k0);
    acc0 = __builtin_amdgcn_mfma_f32_32x32x16_bf16(a, b0, acc0, 0, 0, 0);
    acc1 = __builtin_amdgcn_mfma_f32_32x32x16_bf16(a, b1, acc1, 0, 0, 0);
  }
  __syncthreads();  // k-loop reads of Al done; reuse Al as C tile

  const float bias0 = bias[c0 + lane31];
  const float bias1 = bias[c0 + 32 + lane31];
  float s0 = 0.f, q0 = 0.f, s1 = 0.f, q1 = 0.f;
  #pragma unroll
  for (int r = 0; r < 16; ++r) {
    const int row = mrow + (r & 3) + 8 * (r >> 2) + 4 * khalf;
    const float v0 = acc0[r] + bias0;
    const float v1 = acc1[r] + bias1;
    *(unsigned short*)(Al + swz(row, (c0 + lane31) * 2)) = f2b(v0);
    *(unsigned short*)(Al + swz(row, (c0 + 32 + lane31) * 2)) = f2b(v1);
    if (row0 + row < n) {
      s0 += v0; q0 = fmaf(v0, v0, q0);
      s1 += v1; q1 = fmaf(v1, v1, q1);
    }
  }
  atomicAdd(&colsum[c0 + lane31], s0);
  atomicAdd(&colsq[c0 + lane31], q0);
  atomicAdd(&colsum[c0 + 32 + lane31], s1);
  atomicAdd(&colsq[c0 + 32 + lane31], q1);
  __syncthreads();

  #pragma unroll
  for (int ii = 0; ii < 4; ++ii) {
    const int i = t + ii * 256;
    const int r = i >> 4;
    const int u = (i & 15) << 4;
    const int gr = row0 + r;
    if (gr < n)
      *(uint4*)((char*)C + (size_t)gr * 256 + u) = *(const uint4*)(Al + swz(r, u));
  }
  if (t < 128) {
    const int slot = blockIdx.x & (NSLOT - 1);
    atomicAdd(&psum[slot * 128 + t], colsum[t]);
    atomicAdd(&psq[slot * 128 + t], colsq[t]);
  }
}

// ---------------------------------------------------------------------------
// h0 GEMM (fp32 x -> bf16), 64-row tile, packed epilogue
// ---------------------------------------------------------------------------
__global__ __launch_bounds__(256) void gemm3(
    const float* __restrict__ x, const unsigned short* __restrict__ Wt,
    const float* __restrict__ bias, unsigned short* __restrict__ C, int n) {
  __shared__ char Al[16384];
  const int t = threadIdx.x;
  const int row0 = blockIdx.x * 64;

  #pragma unroll
  for (int ii = 0; ii < 4; ++ii) {
    const int i = t + ii * 256;
    const int r = i >> 4;
    const int u = (i & 15) << 4;
    const int gr = row0 + r;
    uint4 v = make_uint4(0u, 0u, 0u, 0u);
    if (gr < n) {
      const float4 f0 = *(const float4*)(x + (size_t)gr * 128 + (u >> 1));
      const float4 f1 = *(const float4*)(x + (size_t)gr * 128 + (u >> 1) + 4);
      v.x = pack2(f0.x, f0.y); v.y = pack2(f0.z, f0.w);
      v.z = pack2(f1.x, f1.y); v.w = pack2(f1.z, f1.w);
    }
    *(uint4*)(Al + swz(r, u)) = v;
  }
  __syncthreads();

  const int w = t >> 6;
  const int l = t & 63;
  const int lane31 = l & 31;
  const int khalf = l >> 5;
  const int mrow = (w & 1) * 32;
  const int c0 = (w >> 1) * 64;

  f32x16 acc0, acc1;
  #pragma unroll
  for (int i = 0; i < 16; ++i) { acc0[i] = 0.f; acc1[i] = 0.f; }

  const unsigned short* Bp0 = Wt + (size_t)(c0 + lane31) * 128 + 8 * khalf;
  const unsigned short* Bp1 = Wt + (size_t)(c0 + 32 + lane31) * 128 + 8 * khalf;

  #pragma unroll
  for (int k0 = 0; k0 < 128; k0 += 16) {
    const int kb = (k0 + 8 * khalf) * 2;
    const bf16x8 a  = *(const bf16x8*)(Al + swz(mrow + lane31, kb));
    const bf16x8 b0 = *(const bf16x8*)(Bp0 + k0);
    const bf16x8 b1 = *(const bf16x8*)(Bp1 + k0);
    acc0 = __builtin_amdgcn_mfma_f32_32x32x16_bf16(a, b0, acc0, 0, 0, 0);
    acc1 = __builtin_amdgcn_mfma_f32_32x32x16_bf16(a, b1, acc1, 0, 0, 0);
  }
  __syncthreads();

  const float bias0 = bias[c0 + lane31];
  const float bias1 = bias[c0 + 32 + lane31];
  #pragma unroll
  for (int r = 0; r < 16; ++r) {
    const int row = mrow + (r & 3) + 8 * (r >> 2) + 4 * khalf;
    *(unsigned short*)(Al + swz(row, (c0 + lane31) * 2)) = f2b(acc0[r] + bias0);
    *(unsigned short*)(Al + swz(row, (c0 + 32 + lane31) * 2)) = f2b(acc1[r] + bias1);
  }
  __syncthreads();
  #pragma unroll
  for (int ii = 0; ii < 4; ++ii) {
    const int i = t + ii * 256;
    const int r = i >> 4;
    const int u = (i & 15) << 4;
    const int gr = row0 + r;
    if (gr < n)
      *(uint4*)((char*)C + (size_t)gr * 256 + u) = *(const uint4*)(Al + swz(r, u));
  }
}

// ---------------------------------------------------------------------------
// Fused setup: weight conversion + cnt/stats zero + graph segment search
// ---------------------------------------------------------------------------
__global__ __launch_bounds__(256) void setup_k(
    const float* __restrict__ lw, const float* __restrict__ w1,
    const float* __restrict__ w2, unsigned short* __restrict__ Wt,
    const int* __restrict__ batch, int* __restrict__ gstart,
    float* __restrict__ counts, int* __restrict__ cnt,
    float* __restrict__ stats) {
  const int b = blockIdx.x, t = threadIdx.x;
  if (b < 320) {  // weight convert (5*16384)
    const int i = b * 256 + t;
    const int m = i >> 14, r = i & 16383;
    const int ncol = r >> 7, k = r & 127;
    const float* src = (m == 0) ? lw : (m <= 2) ? (w1 + (m - 1) * 16384)
                                                : (w2 + (m - 3) * 16384);
    Wt[i] = f2b(src[k * 128 + ncol]);
  } else if (b < 516) {  // zero cnt (50000)
    const int i = (b - 320) * 256 + t;
    if (i < NN) cnt[i] = 0;
  } else if (b < 580) {  // zero stats (4*4096)
    stats[(b - 516) * 256 + t] = 0.f;
  } else {  // segments (NG+1)
    const int g = (b - 580) * 256 + t;
    if (g > NG) return;
    int lo = 0, hi = NN;
    while (lo < hi) { int m = (lo + hi) >> 1; if (batch[m] < g) lo = m + 1; else hi = m; }
    gstart[g] = lo;
    if (g < NG) {
      int lo1 = lo, hi1 = NN;
      while (lo1 < hi1) { int m = (lo1 + hi1) >> 1; if (batch[m] < g + 1) lo1 = m + 1; else hi1 = m; }
      counts[g] = (float)(lo1 - lo);
    }
  }
}

// ---------------------------------------------------------------------------
// CSR build: histogram -> scan1 (per-block) -> scan23 -> bucket fill
// ---------------------------------------------------------------------------
__global__ __launch_bounds__(256) void edge_hist(const int* __restrict__ ei,
                                                 int* __restrict__ cnt) {
  const int e = blockIdx.x * 256 + threadIdx.x;
  if (e >= NE) return;
  atomicAdd(&cnt[ei[NE + e]], 1);
}

__global__ __launch_bounds__(256) void scan1(const int* __restrict__ cnt,
                                             int* __restrict__ rowptr,
                                             int* __restrict__ bsum) {
  __shared__ int s[256];
  const int b = blockIdx.x, t = threadIdx.x;
  const int i = b * 256 + t;
  const int v = (i < NN) ? cnt[i] : 0;
  s[t] = v;
  __syncthreads();
  for (int off = 1; off < 256; off <<= 1) {
    const int x = (t >= off) ? s[t - off] : 0;
    __syncthreads();
    s[t] += x;
    __syncthreads();
  }
  if (i < NN) rowptr[i] = s[t] - v;
  if (t == 255) bsum[b] = s[255];
}

// scan2+scan3 fused: every block recomputes the 196-entry block prefix
__global__ __launch_bounds__(256) void scan23(int* __restrict__ rowptr,
                                              const int* __restrict__ bsum,
                                              int* __restrict__ cursor) {
  __shared__ int s[256];
  const int blk = blockIdx.x, t = threadIdx.x;
  const int v = (t < SCAN_B) ? bsum[t] : 0;
  s[t] = v;
  __syncthreads();
  for (int off = 1; off < 256; off <<= 1) {
    const int x = (t >= off) ? s[t - off] : 0;
    __syncthreads();
    s[t] += x;
    __syncthreads();
  }
  const int boff = s[blk] - bsum[blk];  // exclusive prefix for this block
  const int i = blk * 256 + t;
  if (i < NN) {
    const int r = rowptr[i] + boff;
    rowptr[i] = r;
    cursor[i] = r;
  }
  if (blk == SCAN_B - 1 && t == 0) rowptr[NN] = s[255];
}

// writes packed entries: src | ((dst&31)<<25)
__global__ __launch_bounds__(256) void build_csr(const int* __restrict__ ei,
                                                 int* __restrict__ cursor,
                                                 int* __restrict__ pck) {
  const int e = blockIdx.x * 256 + threadIdx.x;
  if (e >= NE) return;
  const int src = ei[e];
  const int dst = ei[NE + e];
  const int pos = atomicAdd(&cursor[dst], 1);
  pck[pos] = src | ((dst & 31) << 25);
}

// ---------------------------------------------------------------------------
// Per-graph fused BN+ReLU+mean-pool (bf16 in); BN derived inline.
// WRITE_H: writes h = relu(bn(Z)) for next layer. FINAL: emits out[g].
// ---------------------------------------------------------------------------
template <bool WRITE_H, bool FINAL>
__global__ __launch_bounds__(256) void bn_relu_pool_seg_b(
    const unsigned short* __restrict__ Z, const float* __restrict__ stIn,
    const float* __restrict__ gIn, const float* __restrict__ beIn,
    const int* __restrict__ gstart, unsigned short* __restrict__ h,
    float* __restrict__ pooled, int layerOff,
    const float* __restrict__ counts, const float* __restrict__ jkw,
    const float* __restrict__ jkb, float* __restrict__ out) {
  __shared__ float sc_s[128], sh_s[128];
  __shared__ float red[256 * 8];
  const int g = blockIdx.x;
  const int t = threadIdx.x;
  if (t < 128) {
    float a, b;
    bn_from_stats(stIn, gIn, beIn, t, a, b);
    sc_s[t] = a; sh_s[t] = b;
  }
  __syncthreads();
  const int r0 = gstart[g], r1 = gstart[g + 1];
  const int q = t & 15;
  const int rr = t >> 4;
  const int c0 = q * 8;
  float sc[8], sh[8], acc[8];
  #pragma unroll
  for (int i = 0; i < 8; ++i) { sc[i] = sc_s[c0 + i]; sh[i] = sh_s[c0 + i]; acc[i] = 0.f; }
  for (int r = r0 + rr; r < r1; r += 16) {
    const uint4 v = ((const uint4*)Z)[(size_t)r * 16 + q];
    float o[8];
    o[0] = b2f_lo(v.x); o[1] = b2f_hi(v.x); o[2] = b2f_lo(v.y); o[3] = b2f_hi(v.y);
    o[4] = b2f_lo(v.z); o[5] = b2f_hi(v.z); o[6] = b2f_lo(v.w); o[7] = b2f_hi(v.w);
    #pragma unroll
    for (int i = 0; i < 8; ++i) {
      o[i] = fmaxf(fmaf(o[i], sc[i], sh[i]), 0.f);
      acc[i] += o[i];
    }
    if (WRITE_H) {
      uint4 ov;
      ov.x = pack2(o[0], o[1]); ov.y = pack2(o[2], o[3]);
      ov.z = pack2(o[4], o[5]); ov.w = pack2(o[6], o[7]);
      ((uint4*)h)[(size_t)r * 16 + q] = ov;
    }
  }
  #pragma unroll
  for (int i = 0; i < 8; ++i) red[t * 8 + i] = acc[i];
  __syncthreads();
  for (int off = 8; off >= 1; off >>= 1) {
    if (rr < off) {
      #pragma unroll
      for (int i = 0; i < 8; ++i)
        red[t * 8 + i] += red[(t + off * 16) * 8 + i];
    }
    __syncthreads();
  }
  if (!FINAL) {
    if (rr == 0) {
      #pragma unroll
      for (int i = 0; i < 8; ++i)
        pooled[(size_t)g * 256 + layerOff + c0 + i] = red[t * 8 + i];
    }
  } else {
    float part = 0.f;
    if (t < 128)
      part = pooled[(size_t)g * 256 + t] * jkw[t] + red[t] * jkw[128 + t];
    red[1024 + t] = part;
    __syncthreads();
    for (int off = 64; off >= 1; off >>= 1) {
      if (t < off) red[1024 + t] += red[1024 + t + off];
      __syncthreads();
    }
    if (t == 0)
      out[g] = red[1024] / fmaxf(counts[g], 1.f) + jkb[0];
  }
}

// ---------------------------------------------------------------------------
extern "C" void kernel_launch(void* const* d_in, const int* in_sizes, int n_in,
                              void* d_out, int out_size, void* d_ws,
                              size_t ws_size, hipStream_t stream) {
  const float* x     = (const float*)d_in[0];
  const int*   ei    = (const int*)d_in[1];
  const int*   batch = (const int*)d_in[2];
  const float* lin_w = (const float*)d_in[3];
  const float* lin_b = (const float*)d_in[4];
  const float* w1    = (const float*)d_in[5];
  const float* b1    = (const float*)d_in[6];
  const float* g1    = (const float*)d_in[7];
  const float* be1   = (const float*)d_in[8];
  const float* w2    = (const float*)d_in[9];
  const float* b2    = (const float*)d_in[10];
  const float* g2    = (const float*)d_in[11];
  const float* be2   = (const float*)d_in[12];
  const float* jkw   = (const float*)d_in[13];
  const float* jkb   = (const float*)d_in[14];
  float* out = (float*)d_out;

  char* base = (char*)d_ws;
  unsigned short* hb  = (unsigned short*)base;                 // NN*128 bf16 (A)
  unsigned short* agb = hb + (size_t)NN * 128;                 // NN*128 bf16 (B)
  unsigned short* WtA = agb + (size_t)NN * 128;                // 5*16384 bf16
  float* pooled = (float*)(WtA + 5 * 16384);                   // NG*256
  float* counts = pooled + (size_t)NG * 256;                   // NG
  int* gstart = (int*)(counts + NG);                           // NG+1 (+pad)
  int* rowptr = gstart + NG + 4;                               // NN+1 (+pad)
  int* bsum   = rowptr + NN + 4;                               // 196 (+pad)
  int* pck    = bsum + 200;                                    // NE
  int* cnt    = pck + NE;                                      // NN   (zeroed)
  float* stats = (float*)(cnt + NN);                           // 4*4096 (zeroed)
  // stats set s (0..3): psum = stats + s*4096, psq = psum + 2048

  setup_k<<<583, 256, 0, stream>>>(lin_w, w1, w2, WtA, batch, gstart, counts,
                                   cnt, stats);

  edge_hist<<<(NE + 255) / 256, 256, 0, stream>>>(ei, cnt);
  scan1<<<SCAN_B, 256, 0, stream>>>(cnt, rowptr, bsum);
  scan23<<<SCAN_B, 256, 0, stream>>>(rowptr, bsum, cnt);
  build_csr<<<(NE + 255) / 256, 256, 0, stream>>>(ei, cnt, pck);

  const int gemm_grid = (NN + 63) / 64;      // 782
  const int gath_grid = (NN + 31) / 32;      // 1563

  float* st1_0 = stats;
  float* st2_0 = stats + 4096;
  float* st1_1 = stats + 2 * 4096;
  float* st2_1 = stats + 3 * 4096;

  // h0 = x @ lin_w + lin_b  -> A
  gemm3<<<gemm_grid, 256, 0, stream>>>(x, WtA, lin_b, hb, NN);

  // ---- layer 0 ----
  gemm_gather32<<<gath_grid, 256, 0, stream>>>(
      hb, rowptr, pck, WtA + 1 * 16384, b1, agb, st1_0, st1_0 + 2048, NN);
  gemm_bn<<<gemm_grid, 256, 0, stream>>>(
      agb, st1_0, g1, be1, WtA + 3 * 16384, b2, agb, st2_0, st2_0 + 2048, NN);
  bn_relu_pool_seg_b<true, false><<<NG, 256, 0, stream>>>(
      agb, st2_0, g2, be2, gstart, hb, pooled, 0,
      nullptr, nullptr, nullptr, nullptr);

  // ---- layer 1 ----
  gemm_gather32<<<gath_grid, 256, 0, stream>>>(
      hb, rowptr, pck, WtA + 2 * 16384, b1 + 128, agb, st1_1, st1_1 + 2048, NN);
  gemm_bn<<<gemm_grid, 256, 0, stream>>>(
      agb, st1_1, g1 + 128, be1 + 128, WtA + 4 * 16384, b2 + 128, agb,
      st2_1, st2_1 + 2048, NN);
  bn_relu_pool_seg_b<false, true><<<NG, 256, 0, stream>>>(
      agb, st2_1, g2 + 128, be2 + 128, gstart, nullptr, pooled, 128,
      counts, jkw, jkb, out);
}